// Round 9
// baseline (635.327 us; speedup 1.0000x reference)
//
#include <hip/hip_runtime.h>

typedef unsigned short u16;
typedef unsigned char u8;
typedef unsigned int u32;
typedef float f32x4 __attribute__((ext_vector_type(4)));
typedef __bf16 bf16x8 __attribute__((ext_vector_type(8)));
typedef int i32x8 __attribute__((ext_vector_type(8)));

// MX scale bytes (E8M0: 2^(b-127)): A-side 2^-8 (S matrices quantized x256).
// B-side: 1.0 for X inputs (0x7F); 2^-5 for Z2q (quantized x32, 0x7A).
#define SCL_A 0x77777777u
#define SCL_B1 0x7F7F7F7Fu
#define SCL_B32 0x7A7A7A7Au

// ---------- helpers ----------
__device__ __forceinline__ u16 f2bf(float f){
  u32 u = __builtin_bit_cast(u32, f);
  u32 r = (u + 0x7fffu + ((u >> 16) & 1u)) >> 16;
  return (u16)r;
}
__device__ __forceinline__ float bf2f(u16 h){
  return __builtin_bit_cast(float, ((u32)h) << 16);
}
__device__ __forceinline__ u8 f2e4(float x){
  return (u8)(__builtin_amdgcn_cvt_pk_fp8_f32(x, x, 0, false) & 0xff);
}
__device__ __forceinline__ u32 pack4_e4(float a, float b, float c, float d){
  int w = __builtin_amdgcn_cvt_pk_fp8_f32(a, b, 0, false);
  w = __builtin_amdgcn_cvt_pk_fp8_f32(c, d, w, true);
  return (u32)w;
}
__device__ __forceinline__ void gl_lds16(const void* g, void* l){
  __builtin_amdgcn_global_load_lds((__attribute__((address_space(1))) void*)g,
                                   (__attribute__((address_space(3))) void*)l,
                                   16, 0, 0);
}
__device__ __forceinline__ float sigf(float x){ return 1.f/(1.f + __expf(-x)); }

// XCD-chunked block swizzle (T1). Requires nwg % 8 == 0 (all swizzled grids:
// 864/1536/768/288/512/256/512-pre). Remap hw id -> contiguous logical chunk
// per XCD so each XCD's 4MB L2 holds a slab of A instead of thrashing all ops.
__device__ __forceinline__ void xcd_swizzle(int& x, int& y, int& z){
  int gx = gridDim.x, gy = gridDim.y;
  int nwg = gx * gy * gridDim.z;
  int lid = blockIdx.x + gx*(blockIdx.y + gy*blockIdx.z);
  int cpx = nwg >> 3;
  int swz = (lid & 7)*cpx + (lid >> 3);
  x = swz % gx;
  int rest = swz / gx;
  y = rest % gy;
  z = rest / gy;
}

// ---------- sums ----------
__global__ __launch_bounds__(256) void k_rowsum(const float* __restrict__ adj, float* __restrict__ inv_rs,
                                                float* __restrict__ cs){
  int j = blockIdx.x; int tid = threadIdx.x;
  float s = 0.f;
  for (int i = tid; i < 2048; i += 256) s += adj[(long)j*2048 + i];
  for (int off = 32; off; off >>= 1) s += __shfl_down(s, off, 64);
  __shared__ float red[4];
  if ((tid & 63) == 0) red[tid >> 6] = s;
  __syncthreads();
  if (tid == 0){
    float t = red[0] + red[1] + red[2] + red[3];
    inv_rs[j] = 1.f / fmaxf(t, 1e-8f);
    cs[j] = 0.f;   // zero for k_colsum2's atomics (stream-ordered after this kernel)
  }
}

__global__ __launch_bounds__(256) void k_colsum2(const float* __restrict__ adj, float* __restrict__ cs){
  int j0 = blockIdx.x * 64, i0 = blockIdx.y * 128;
  int jj = threadIdx.x & 63, w = threadIdx.x >> 6;
  float s = 0.f;
  for (int i = w; i < 128; i += 4) s += adj[(long)(i0+i)*2048 + j0 + jj];
  __shared__ float red[256];
  red[threadIdx.x] = s;
  __syncthreads();
  if (w == 0){
    float t = red[jj] + red[64+jj] + red[128+jj] + red[192+jj];
    atomicAdd(&cs[j0+jj], t);
  }
}

// Merged S-build: one adj tile read -> S0T[j][i]=adj[j][i]*inv_rs[j],
// S1[j][i]=adj[j][i]/max(cs[i],eps) (+fp8 S1q x256, inline, coalesced)
// and S0[i][j] (+fp8 S0q x256) via LDS transpose.
__global__ __launch_bounds__(256) void k_build_S(const float* __restrict__ adj,
                                                 const float* __restrict__ inv_rs,
                                                 const float* __restrict__ cs,
                                                 u16* __restrict__ S0, u8* __restrict__ S0q,
                                                 u16* __restrict__ S0T, u16* __restrict__ S1,
                                                 u8* __restrict__ S1q){
  __shared__ float t[64*66];
  __shared__ float rsl[64];
  __shared__ float icl[64];
  int i0 = blockIdx.x * 64, j0 = blockIdx.y * 64;
  int tid = threadIdx.x;
  if (tid < 64) rsl[tid] = inv_rs[j0 + tid];
  else if (tid >= 64 && tid < 128) icl[tid-64] = 1.f / fmaxf(cs[i0 + tid-64], 1e-8f);
  __syncthreads();
  for (int e = tid; e < 4096; e += 256){
    int jj = e >> 6, ii = e & 63;                 // lane varies ii: adj read + S0T/S1 writes coalesced
    float a = adj[(long)(j0+jj)*2048 + i0 + ii];
    t[jj*66 + ii] = a;
    long o = (long)(j0+jj)*2048 + i0 + ii;
    S0T[o] = f2bf(a * rsl[jj]);                   // jj uniform per wave -> LDS broadcast
    float s1v = a * icl[ii];
    S1[o]  = f2bf(s1v);
    S1q[o] = f2e4(s1v * 256.f);
  }
  __syncthreads();
  for (int e = tid; e < 4096; e += 256){
    int ii = e >> 6, jj = e & 63;                 // lane varies jj: S0/S0q writes coalesced
    u16 vb = f2bf(t[jj*66 + ii] * rsl[jj]);       // LDS stride 66: 2-way bank alias (free, m136)
    long o = (long)(i0+ii)*2048 + j0 + jj;
    S0[o] = vb;
    S0q[o] = f2e4(bf2f(vb)*256.f);
  }
}

// Merged weight pack: z selects {wg0,wc0,wg1,wc1}. WT[o][k]=w[(f*5+m)*OUTr+o],
// k=(m,f) with per-z (OUTr,F,Fp,Kd); zero-padded.
__global__ __launch_bounds__(256) void k_packW4(const float* __restrict__ wg0, const float* __restrict__ wc0,
                                                const float* __restrict__ wg1, const float* __restrict__ wc1,
                                                u16* __restrict__ WTg0, u16* __restrict__ WTc0,
                                                u16* __restrict__ WTg1, u16* __restrict__ WTc1){
  int z = blockIdx.y;
  const float* w = (z==0) ? wg0 : (z==1) ? wc0 : (z==2) ? wg1 : wc1;
  u16* WT       = (z==0) ? WTg0 : (z==1) ? WTc0 : (z==2) ? WTg1 : WTc1;
  int OUTr = (z==0 || z==2) ? 128 : 64;
  int F  = (z < 2) ? 65 : 128;
  int Fp = (z < 2) ? 72 : 128;
  int Kd = (z < 2) ? 384 : 640;
  int idx = blockIdx.x*256 + threadIdx.x;
  if (idx >= 128*Kd) return;
  int o = idx / Kd, k = idx - o*Kd;
  int m = k / Fp, f = k - m*Fp;
  float v = 0.f;
  if (o < OUTr && m < 5 && f < F) v = w[(long)(f*5 + m)*OUTr + o];
  WT[idx] = f2bf(v);
}

// hidden (f32) -> fp8 X0T rows (b, rowoff+u) + bf16 D cols (coloff+u); layer-0 extras: inp + pads
__global__ __launch_bounds__(256) void k_hx_build(const float* __restrict__ hx, const float* __restrict__ inp,
                                                  u8* __restrict__ X0T, u16* __restrict__ D,
                                                  int Fp, int rowoff, long ldD, int coloff, int l0extras){
  __shared__ float t[64*66];
  int b = blockIdx.x, n0 = blockIdx.y * 64;
  int tid = threadIdx.x;
  const float* hb = hx + (long)b*2048*64;
  long bn0 = (long)b*2048 + n0;
  for (int e = tid; e < 4096; e += 256){
    int u = e & 63, ni = e >> 6;            // lane->u: f32 read coalesced
    t[ni*66 + u] = hb[(long)(n0+ni)*64 + u];
  }
  __syncthreads();
  for (int e = tid; e < 4096; e += 256){
    int u = e >> 6, ni = e & 63;            // lane->ni: fp8 row write coalesced
    X0T[((long)b*Fp + rowoff + u)*2048 + n0 + ni] = f2e4(t[ni*66 + u]);
  }
  for (int e = tid; e < 4096; e += 256){
    int ni = e >> 6, u = e & 63;            // lane->u: D col write coalesced
    D[(bn0 + ni)*ldD + coloff + u] = f2bf(t[ni*66 + u]);
  }
  if (l0extras){
    if (tid < 64){
      float v = inp[(long)b*2048 + n0 + tid];
      X0T[((long)b*Fp)*2048 + n0 + tid] = f2e4(v);
      D[(bn0 + tid)*ldD] = f2bf(v);
    }
    for (int e = tid; e < 7*64; e += 256){
      int f = 65 + (e >> 6), ni = e & 63;
      X0T[((long)b*Fp + f)*2048 + n0 + ni] = 0;
    }
    for (int e = tid; e < 64*31; e += 256){
      int ni = e / 31, wc = e - ni*31;
      int col = (wc < 7) ? (65 + wc) : (353 + wc);   // {65..71, 360..383}
      D[(bn0 + ni)*ldD + col] = 0;
    }
  }
}

// ---------- bf16 GEMM core, BK=64 (precompute + dense) ----------
__device__ __forceinline__ void gemm_core(const u16* __restrict__ A, const u16* __restrict__ Bt,
                                          int K, long tM, long tC,
                                          u16* lA, u16* lB, f32x4 (&acc)[4][4]){
  int tid = threadIdx.x;
  int wv = tid >> 6, lane = tid & 63;
  int q = lane >> 4, r16 = lane & 15;

  const u16* ga[4]; const u16* gb[4];
  u16* la[4]; u16* lb[4];
  #pragma unroll
  for (int it = 0; it < 4; it++){
    int L = it*256 + tid;
    int r = L >> 3, g = (L & 7) ^ (r & 7);
    ga[it] = A  + (tM + r)*(long)K + g*8;
    gb[it] = Bt + (tC + r)*(long)K + g*8;
    la[it] = lA + (it*256 + wv*64)*8;
    lb[it] = lB + (it*256 + wv*64)*8;
  }

  #pragma unroll
  for (int i = 0; i < 4; i++)
    #pragma unroll
    for (int j = 0; j < 4; j++){ acc[i][j][0]=0.f; acc[i][j][1]=0.f; acc[i][j][2]=0.f; acc[i][j][3]=0.f; }

  int wm = wv & 1, wn = wv >> 1;
  int aoff[4][2], boff[4][2];
  #pragma unroll
  for (int s = 0; s < 4; s++){
    int m = wm*64 + s*16 + r16;
    int n = wn*64 + s*16 + r16;
    #pragma unroll
    for (int h = 0; h < 2; h++){
      aoff[s][h] = (m*8 + ((h*4 + q) ^ (m & 7))) * 8;
      boff[s][h] = (n*8 + ((h*4 + q) ^ (n & 7))) * 8;
    }
  }

  for (int k0 = 0; k0 < K; k0 += 64){
    __syncthreads();
    #pragma unroll
    for (int it = 0; it < 4; it++){
      gl_lds16(ga[it] + k0, la[it]);
      gl_lds16(gb[it] + k0, lb[it]);
    }
    asm volatile("s_waitcnt vmcnt(0)" ::: "memory");
    __syncthreads();
    #pragma unroll
    for (int h = 0; h < 2; h++){
      bf16x8 af[4], bfr[4];
      #pragma unroll
      for (int s = 0; s < 4; s++){
        af[s]  = *(const bf16x8*)&lA[aoff[s][h]];
        bfr[s] = *(const bf16x8*)&lB[boff[s][h]];
      }
      #pragma unroll
      for (int i = 0; i < 4; i++)
        #pragma unroll
        for (int j = 0; j < 4; j++)
          acc[i][j] = __builtin_amdgcn_mfma_f32_16x16x32_bf16(af[i], bfr[j], acc[i][j], 0, 0, 0);
    }
  }
}

// ---------- fp8 MX GEMM core, BK=128 bytes ----------
// Storage permutation sigma(g) = (g>>1)|((g&1)<<2): frag-read slot pattern
// (e*4+q)^(m&7), measured SQ_LDS_BANK_CONFLICT = 0. SCLB: B-operand MX scale
// (0x7F..=1.0 for X, 0x7A..=2^-5 for Z2q quantized x32).
template<u32 SCLB>
__device__ __forceinline__ void gemm_core8(const u8* __restrict__ A, const u8* __restrict__ Bt,
                                           int K, long tM, long tC,
                                           u8* lA, u8* lB, f32x4 (&acc)[4][4]){
  int tid = threadIdx.x;
  int wv = tid >> 6, lane = tid & 63;
  int q = lane >> 4, r16 = lane & 15;

  const u8* ga[4]; const u8* gb[4];
  u8* la[4]; u8* lb[4];
  #pragma unroll
  for (int it = 0; it < 4; it++){
    int L = it*256 + tid;
    int r = L >> 3, x = (L & 7) ^ (r & 7);
    int g = ((x & 3) << 1) | (x >> 2);     // sigma^-1
    ga[it] = A  + (tM + r)*(long)K + g*16;
    gb[it] = Bt + (tC + r)*(long)K + g*16;
    la[it] = lA + (it*256 + wv*64)*16;
    lb[it] = lB + (it*256 + wv*64)*16;
  }

  #pragma unroll
  for (int i = 0; i < 4; i++)
    #pragma unroll
    for (int j = 0; j < 4; j++){ acc[i][j][0]=0.f; acc[i][j][1]=0.f; acc[i][j][2]=0.f; acc[i][j][3]=0.f; }

  int wm = wv & 1, wn = wv >> 1;
  int aoff[4][2], boff[4][2];
  #pragma unroll
  for (int s = 0; s < 4; s++){
    int m = wm*64 + s*16 + r16;
    int n = wn*64 + s*16 + r16;
    #pragma unroll
    for (int e = 0; e < 2; e++){
      aoff[s][e] = m*128 + ((e*4 + q) ^ (m & 7)) * 16;
      boff[s][e] = n*128 + ((e*4 + q) ^ (n & 7)) * 16;
    }
  }

  for (int k0 = 0; k0 < K; k0 += 128){
    __syncthreads();
    #pragma unroll
    for (int it = 0; it < 4; it++){
      gl_lds16(ga[it] + k0, la[it]);
      gl_lds16(gb[it] + k0, lb[it]);
    }
    asm volatile("s_waitcnt vmcnt(0)" ::: "memory");
    __syncthreads();
    i32x8 af[4], bfr[4];
    #pragma unroll
    for (int s = 0; s < 4; s++){
      uint4 a0 = *(const uint4*)&lA[aoff[s][0]];
      uint4 a1 = *(const uint4*)&lA[aoff[s][1]];
      i32x8 av; av[0]=a0.x; av[1]=a0.y; av[2]=a0.z; av[3]=a0.w; av[4]=a1.x; av[5]=a1.y; av[6]=a1.z; av[7]=a1.w;
      af[s] = av;
      uint4 b0 = *(const uint4*)&lB[boff[s][0]];
      uint4 b1 = *(const uint4*)&lB[boff[s][1]];
      i32x8 bv; bv[0]=b0.x; bv[1]=b0.y; bv[2]=b0.z; bv[3]=b0.w; bv[4]=b1.x; bv[5]=b1.y; bv[6]=b1.z; bv[7]=b1.w;
      bfr[s] = bv;
    }
    #pragma unroll
    for (int i = 0; i < 4; i++)
      #pragma unroll
      for (int j = 0; j < 4; j++)
        acc[i][j] = __builtin_amdgcn_mfma_scale_f32_16x16x128_f8f6f4(
                      af[i], bfr[j], acc[i][j], 0, 0, 0, SCL_A, 0, SCLB);
  }
}

// ---------- precompute: z=0: R=S1@S0 -> Rq(e4m3 x256); z=1: V=2*S0^2-I -> Vq ----------
__global__ __launch_bounds__(256) void gemm_pre(const u16* __restrict__ S0T, const u16* __restrict__ S1,
                                                const u16* __restrict__ S0,
                                                u8* __restrict__ Rq, u8* __restrict__ Vq){
  __shared__ u16 lA[8192];
  __shared__ u16 lB[8192];
  f32x4 acc[4][4];
  int bx, by, bz;
  xcd_swizzle(bx, by, bz);
  const u16* Bt = (bz == 0) ? S1 : S0;
  long tM = (long)bx * 128, tC = (long)by * 128;
  gemm_core(S0T, Bt, 2048, tM, tC, lA, lB, acc);

  int tid = threadIdx.x, wv = tid >> 6, lane = tid & 63;
  int q = lane >> 4, r16 = lane & 15, wm = wv & 1, wn = wv >> 1;
  #pragma unroll
  for (int i = 0; i < 4; i++){
    long gi = tM + wm*64 + i*16 + q*4;
    #pragma unroll
    for (int j = 0; j < 4; j++){
      long gc = tC + wn*64 + j*16 + r16;
      f32x4 v = acc[i][j];
      if (bz == 0){
        *(u32*)(Rq + gc*2048 + gi) = pack4_e4(v[0]*256.f, v[1]*256.f, v[2]*256.f, v[3]*256.f);
      } else {
        float x0 = 2.f*v[0] - ((gi+0) == gc ? 1.f : 0.f);
        float x1 = 2.f*v[1] - ((gi+1) == gc ? 1.f : 0.f);
        float x2 = 2.f*v[2] - ((gi+2) == gc ? 1.f : 0.f);
        float x3 = 2.f*v[3] - ((gi+3) == gc ? 1.f : 0.f);
        *(u32*)(Vq + gc*2048 + gi) = pack4_e4(x0*256.f, x1*256.f, x2*256.f, x3*256.f);
      }
    }
  }
}

// ---------- fp8 diffusion stage 1 (gate): z in {0,1,2} = {S0,V,R}; D slice z+1;
// z==2 also emits Z2q = e4m3(z2 x32) as B-operand for stage 2 ----------
template<int FP>
__global__ __launch_bounds__(256) void gemm_diff8(const u8* __restrict__ M0, const u8* __restrict__ M1,
                                                  const u8* __restrict__ M2,
                                                  const u8* __restrict__ X, u16* __restrict__ D, long ldD,
                                                  u8* __restrict__ Z2q){
  __shared__ u8 lA[16384];
  __shared__ u8 lB[16384];
  f32x4 acc[4][4];
  int bx, by, z;
  xcd_swizzle(bx, by, z);
  const u8* A = (z == 0) ? M0 : (z == 1) ? M1 : M2;
  long tM = (long)bx * 128, tC = (long)by * 128;
  gemm_core8<SCL_B1>(A, X, 2048, tM, tC, lA, lB, acc);

  int tid = threadIdx.x, wv = tid >> 6, lane = tid & 63;
  int q = lane >> 4, r16 = lane & 15, wm = wv & 1, wn = wv >> 1;
  int zb = (z + 1) * FP;
  #pragma unroll
  for (int i = 0; i < 4; i++){
    long gi = tM + wm*64 + i*16 + q*4;
    #pragma unroll
    for (int j = 0; j < 4; j++){
      int gc = (int)(tC + wn*64 + j*16 + r16);
      int b = gc / FP, f = gc - b*FP;
      long rb = (long)b*2048 + gi;
      f32x4 v = acc[i][j];
      D[(rb+0)*ldD + zb + f] = f2bf(v[0]);
      D[(rb+1)*ldD + zb + f] = f2bf(v[1]);
      D[(rb+2)*ldD + zb + f] = f2bf(v[2]);
      D[(rb+3)*ldD + zb + f] = f2bf(v[3]);
      if (z == 2)
        *(u32*)(Z2q + (long)gc*2048 + gi) = pack4_e4(v[0]*32.f, v[1]*32.f, v[2]*32.f, v[3]*32.f);
    }
  }
}

// ---------- fp8 candidate stage 1: Xr (2048 x 2048), D col (z+1)*Fp+fin+u; z2 -> Z2q ----------
__global__ __launch_bounds__(256) void gemm_diff8_c(const u8* __restrict__ M0, const u8* __restrict__ M1,
                                                    const u8* __restrict__ M2,
                                                    const u8* __restrict__ Xr, u16* __restrict__ D,
                                                    long ldD, int Fp, int fin, u8* __restrict__ Z2q){
  __shared__ u8 lA[16384];
  __shared__ u8 lB[16384];
  f32x4 acc[4][4];
  int bx, by, z;
  xcd_swizzle(bx, by, z);
  const u8* A = (z == 0) ? M0 : (z == 1) ? M1 : M2;
  long tM = (long)bx * 128, tC = (long)by * 128;
  gemm_core8<SCL_B1>(A, Xr, 2048, tM, tC, lA, lB, acc);

  int tid = threadIdx.x, wv = tid >> 6, lane = tid & 63;
  int q = lane >> 4, r16 = lane & 15, wm = wv & 1, wn = wv >> 1;
  int zb = (z + 1) * Fp + fin;
  #pragma unroll
  for (int i = 0; i < 4; i++){
    long gi = tM + wm*64 + i*16 + q*4;
    #pragma unroll
    for (int j = 0; j < 4; j++){
      int gc = (int)(tC + wn*64 + j*16 + r16);
      int b = gc >> 6, u = gc & 63;
      long rb = (long)b*2048 + gi;
      f32x4 v = acc[i][j];
      D[(rb+0)*ldD + zb + u] = f2bf(v[0]);
      D[(rb+1)*ldD + zb + u] = f2bf(v[1]);
      D[(rb+2)*ldD + zb + u] = f2bf(v[2]);
      D[(rb+3)*ldD + zb + u] = f2bf(v[3]);
      if (z == 2)
        *(u32*)(Z2q + (long)gc*2048 + gi) = pack4_e4(v[0]*32.f, v[1]*32.f, v[2]*32.f, v[3]*32.f);
    }
  }
}

// ---------- stage 2 (gate): z3 = W@X = 2*S1@z2 - z0 (chained; replaces Wq precompute) ----------
template<int FP>
__global__ __launch_bounds__(256) void gemm_diff8w(const u8* __restrict__ S1q, const u8* __restrict__ Z2q,
                                                   u16* __restrict__ D, long ldD){
  __shared__ u8 lA[16384];
  __shared__ u8 lB[16384];
  f32x4 acc[4][4];
  int bx, by, bz;
  xcd_swizzle(bx, by, bz);   // gridDim.z == 1 -> bz == 0
  long tM = (long)bx * 128, tC = (long)by * 128;
  gemm_core8<SCL_B32>(S1q, Z2q, 2048, tM, tC, lA, lB, acc);

  int tid = threadIdx.x, wv = tid >> 6, lane = tid & 63;
  int q = lane >> 4, r16 = lane & 15, wm = wv & 1, wn = wv >> 1;
  int zb = 4 * FP;   // z3 slice; z0 slice at FP
  #pragma unroll
  for (int i = 0; i < 4; i++){
    long gi = tM + wm*64 + i*16 + q*4;
    #pragma unroll
    for (int j = 0; j < 4; j++){
      int gc = (int)(tC + wn*64 + j*16 + r16);
      int b = gc / FP, f = gc - b*FP;
      long rb = (long)b*2048 + gi;
      f32x4 v = acc[i][j];
      D[(rb+0)*ldD + zb + f] = f2bf(2.f*v[0] - bf2f(D[(rb+0)*ldD + FP + f]));
      D[(rb+1)*ldD + zb + f] = f2bf(2.f*v[1] - bf2f(D[(rb+1)*ldD + FP + f]));
      D[(rb+2)*ldD + zb + f] = f2bf(2.f*v[2] - bf2f(D[(rb+2)*ldD + FP + f]));
      D[(rb+3)*ldD + zb + f] = f2bf(2.f*v[3] - bf2f(D[(rb+3)*ldD + FP + f]));
    }
  }
}

// ---------- stage 2 (candidate): z3 = 2*S1@z2 - z0, cand column mapping ----------
__global__ __launch_bounds__(256) void gemm_diff8w_c(const u8* __restrict__ S1q, const u8* __restrict__ Z2q,
                                                     u16* __restrict__ D, long ldD, int Fp, int fin){
  __shared__ u8 lA[16384];
  __shared__ u8 lB[16384];
  f32x4 acc[4][4];
  int bx, by, bz;
  xcd_swizzle(bx, by, bz);   // bz == 0
  long tM = (long)bx * 128, tC = (long)by * 128;
  gemm_core8<SCL_B32>(S1q, Z2q, 2048, tM, tC, lA, lB, acc);

  int tid = threadIdx.x, wv = tid >> 6, lane = tid & 63;
  int q = lane >> 4, r16 = lane & 15, wm = wv & 1, wn = wv >> 1;
  int zb = 4*Fp + fin, z0b = Fp + fin;
  #pragma unroll
  for (int i = 0; i < 4; i++){
    long gi = tM + wm*64 + i*16 + q*4;
    #pragma unroll
    for (int j = 0; j < 4; j++){
      int gc = (int)(tC + wn*64 + j*16 + r16);
      int b = gc >> 6, u = gc & 63;
      long rb = (long)b*2048 + gi;
      f32x4 v = acc[i][j];
      D[(rb+0)*ldD + zb + u] = f2bf(2.f*v[0] - bf2f(D[(rb+0)*ldD + z0b + u]));
      D[(rb+1)*ldD + zb + u] = f2bf(2.f*v[1] - bf2f(D[(rb+1)*ldD + z0b + u]));
      D[(rb+2)*ldD + zb + u] = f2bf(2.f*v[2] - bf2f(D[(rb+2)*ldD + z0b + u]));
      D[(rb+3)*ldD + zb + u] = f2bf(2.f*v[3] - bf2f(D[(rb+3)*ldD + z0b + u]));
    }
  }
}

// ---------- dense (bf16): OutT[c][i] = bf16( sum_k A[i,k]*Bt[c,k] ) ----------
__global__ __launch_bounds__(256) void gemm_dense(const u16* __restrict__ A, const u16* __restrict__ Bt,
                                                  u16* __restrict__ Out, int K, long ldOut){
  __shared__ u16 lA[8192];
  __shared__ u16 lB[8192];
  f32x4 acc[4][4];
  long tM = (long)blockIdx.x * 128, tC = (long)blockIdx.y * 128;
  gemm_core(A, Bt, K, tM, tC, lA, lB, acc);

  int tid = threadIdx.x, wv = tid >> 6, lane = tid & 63;
  int q = lane >> 4, r16 = lane & 15, wm = wv & 1, wn = wv >> 1;
  #pragma unroll
  for (int i = 0; i < 4; i++){
    long gi = tM + wm*64 + i*16 + q*4;
    #pragma unroll
    for (int j = 0; j < 4; j++){
      long gc = tC + wn*64 + j*16 + r16;
      f32x4 v = acc[i][j];
      ushort4 o;
      o.x = f2bf(v[0]); o.y = f2bf(v[1]); o.z = f2bf(v[2]); o.w = f2bf(v[3]);
      *(ushort4*)(Out + gc*ldOut + gi) = o;
    }
  }
}

// ---------- GRU epilogues ----------
__global__ __launch_bounds__(256) void k_gate_ep(const u16* __restrict__ GT, const float* __restrict__ bg,
                                                 const float* __restrict__ hid, u8* __restrict__ Xr8,
                                                 u16* __restrict__ D, long ldD, int coloff){
  __shared__ float t[64*66];
  __shared__ u16 tb[64*66];
  int b = blockIdx.x, n0 = blockIdx.y * 64;
  int tid = threadIdx.x;
  long bn0 = (long)b*2048 + n0;
  for (int e = tid; e < 4096; e += 256){
    int u = e & 63, ni = e >> 6;            // lane->u: f32 hid read coalesced
    t[ni*66 + u] = hid[(bn0 + ni)*64 + u];
  }
  __syncthreads();
  for (int e = tid; e < 4096; e += 256){
    int u = e >> 6, ni = e & 63;            // lane->ni: GT read + Xr8 write coalesced
    float r = sigf(bf2f(GT[(long)u*65536 + bn0 + ni]) + bg[u]);
    float pv = r * t[ni*66 + u];
    Xr8[((long)b*64 + u)*2048 + n0 + ni] = f2e4(pv);
    tb[ni*66 + u] = f2bf(pv);
  }
  __syncthreads();
  for (int e = tid; e < 4096; e += 256){
    int ni = e >> 6, u = e & 63;            // lane->u: D col write coalesced
    D[(bn0 + ni)*ldD + coloff + u] = tb[ni*66 + u];
  }
}

__global__ __launch_bounds__(256) void k_cand_ep(const u16* __restrict__ CT, const u16* __restrict__ GT,
                                                 const float* __restrict__ bc, const float* __restrict__ bg,
                                                 const float* __restrict__ hx, float* __restrict__ hout,
                                                 u8* __restrict__ X0T_next, u16* __restrict__ Dnext,
                                                 const float* __restrict__ wproj, const float* __restrict__ bproj,
                                                 float* __restrict__ out){
  __shared__ u16 tc[64*66];
  __shared__ u16 tu[64*66];
  __shared__ u16 th[64*66];
  int b = blockIdx.x, n0 = blockIdx.y * 64;
  int tid = threadIdx.x;
  long bn0 = (long)b*2048 + n0;
  for (int e = tid; e < 4096; e += 256){
    int u = e >> 6, ni = e & 63;
    float cv = tanhf(bf2f(CT[(long)u*65536 + bn0 + ni]) + bc[u]);
    float uv = sigf(bf2f(GT[(long)(64+u)*65536 + bn0 + ni]) + bg[64+u]);
    tc[ni*66 + u] = f2bf(cv);
    tu[ni*66 + u] = f2bf(uv);
  }
  __syncthreads();
  int lane = tid & 63, wv = tid >> 6;
  for (int it = 0; it < 16; ++it){
    int ni = it*4 + wv, u = lane;
    float hxv = hx[(bn0 + ni)*64 + u];
    float uv = bf2f(tu[ni*66 + u]), cv = bf2f(tc[ni*66 + u]);
    float h = uv*hxv + (1.f - uv)*cv;
    hout[(bn0 + ni)*64 + u] = h;
    if (Dnext) Dnext[(bn0 + ni)*640 + u] = f2bf(h);
    th[ni*66 + u] = f2bf(h);
    if (wproj){
      float v = h * wproj[u];
      for (int off = 32; off; off >>= 1) v += __shfl_down(v, off, 64);
      if (lane == 0) out[(long)b*2048 + n0 + ni] = v + bproj[0];
    }
  }
  __syncthreads();
  if (X0T_next){
    for (int e = tid; e < 4096; e += 256){
      int u = e >> 6, ni = e & 63;          // lane->ni: fp8 row write coalesced
      X0T_next[((long)b*128 + u)*2048 + n0 + ni] = f2e4(bf2f(th[ni*66 + u]));
    }
  }
}

// ---------- launch ----------
extern "C" void kernel_launch(void* const* d_in, const int* in_sizes, int n_in,
                              void* d_out, int out_size, void* d_ws, size_t ws_size,
                              hipStream_t stream){
  (void)in_sizes; (void)n_in; (void)out_size; (void)ws_size;
  const float* inputs = (const float*)d_in[0];
  const float* hidden = (const float*)d_in[1];
  const float* adj    = (const float*)d_in[2];
  const float* wg0 = (const float*)d_in[3];
  const float* bg0 = (const float*)d_in[4];
  const float* wc0 = (const float*)d_in[5];
  const float* bc0 = (const float*)d_in[6];
  const float* wg1 = (const float*)d_in[7];
  const float* bg1 = (const float*)d_in[8];
  const float* wc1 = (const float*)d_in[9];
  const float* bc1 = (const float*)d_in[10];
  const float* wp  = (const float*)d_in[11];
  const float* bp  = (const float*)d_in[12];
  float* out = (float*)d_out;

  char* p = (char*)d_ws;
  auto alloc = [&](size_t bytes)->char*{ char* r = p; p += (bytes + 255) & ~(size_t)255; return r; };
  float* inv_rs = (float*)alloc(2048*4);
  float* cs     = (float*)alloc(2048*4);
  const size_t SB  = (size_t)2048*2048*2;   // bf16 NxN
  const size_t SB8 = (size_t)2048*2048;     // fp8 NxN
  u16* S0  = (u16*)alloc(SB);
  u16* S0T = (u16*)alloc(SB);
  u16* S1  = (u16*)alloc(SB);
  u8*  S0q = (u8*)alloc(SB8);
  u8*  S1q = (u8*)alloc(SB8);
  u8*  Rq  = (u8*)alloc(SB8);
  u8*  Vq  = (u8*)alloc(SB8);
  u8*  Z2q = (u8*)alloc((size_t)4096*2048); // z2 output, e4m3 x32, [gc][n]
  u8*  X0a8 = (u8*)alloc((size_t)2304*2048); // layer0 cat, fp8, Fp=72
  u8*  X0b8 = (u8*)alloc((size_t)4096*2048); // layer1 cat, fp8, Fp=128
  u8*  Xr8  = (u8*)alloc(SB8);               // r*hx, fp8
  u16* D   = (u16*)alloc((size_t)65536*640*2);
  u16* GT = (u16*)alloc((size_t)128*65536*2);
  u16* CT = (u16*)alloc((size_t)128*65536*2);
  u16* WTg0 = (u16*)alloc((size_t)128*384*2);
  u16* WTc0 = (u16*)alloc((size_t)128*384*2);
  u16* WTg1 = (u16*)alloc((size_t)128*640*2);
  u16* WTc1 = (u16*)alloc((size_t)128*640*2);

  const float* hid0 = hidden;
  const float* hid1 = hidden + (size_t)4194304;
  float* h0out = out + 65536;
  float* h1out = out + 65536 + 4194304;

  // ---- setup ----
  k_rowsum<<<2048, 256, 0, stream>>>(adj, inv_rs, cs);
  k_colsum2<<<dim3(32,16), 256, 0, stream>>>(adj, cs);
  k_build_S<<<dim3(32,32), 256, 0, stream>>>(adj, inv_rs, cs, S0, S0q, S0T, S1, S1q);
  k_packW4<<<dim3(320,4), 256, 0, stream>>>(wg0, wc0, wg1, wc1, WTg0, WTc0, WTg1, WTc1);
  k_hx_build<<<dim3(32,32), 256, 0, stream>>>(hid0, inputs, X0a8, D, 72, 1, 384, 1, 1);

  // ---- precompute diffusion operators R, V (bf16 compute, fp8 x256 output) ----
  gemm_pre<<<dim3(16,16,2), 256, 0, stream>>>(S0T, S1, S0, Rq, Vq);

  dim3 gD0(16, 18, 3), gD1(16, 32, 3), gDc(16, 16, 3);
  dim3 gW0(16, 18), gW1(16, 32), gWc(16, 16);
  dim3 gDen(512, 1), gE(32, 32);

  // ---- layer 0 gate ----
  gemm_diff8<72><<<gD0, 256, 0, stream>>>(S0q, Vq, Rq, X0a8, D, 384, Z2q);
  gemm_diff8w<72><<<gW0, 256, 0, stream>>>(S1q, Z2q, D, 384);
  gemm_dense<<<gDen, 256, 0, stream>>>(D, WTg0, GT, 384, 65536);
  k_gate_ep<<<gE, 256, 0, stream>>>(GT, bg0, hid0, Xr8, D, 384, 1);

  // ---- layer 0 candidate (diffuse only r*hx; inp cols reused from gate pass) ----
  gemm_diff8_c<<<gDc, 256, 0, stream>>>(S0q, Vq, Rq, Xr8, D, 384, 72, 1, Z2q);
  gemm_diff8w_c<<<gWc, 256, 0, stream>>>(S1q, Z2q, D, 384, 72, 1);
  gemm_dense<<<gDen, 256, 0, stream>>>(D, WTc0, CT, 384, 65536);
  k_cand_ep<<<gE, 256, 0, stream>>>(CT, GT, bc0, bg0, hid0, h0out, X0b8, D, nullptr, nullptr, nullptr);

  // ---- layer 1 build ----
  k_hx_build<<<dim3(32,32), 256, 0, stream>>>(hid1, nullptr, X0b8, D, 128, 64, 640, 64, 0);

  // ---- layer 1 gate ----
  gemm_diff8<128><<<gD1, 256, 0, stream>>>(S0q, Vq, Rq, X0b8, D, 640, Z2q);
  gemm_diff8w<128><<<gW1, 256, 0, stream>>>(S1q, Z2q, D, 640);
  gemm_dense<<<gDen, 256, 0, stream>>>(D, WTg1, GT, 640, 65536);
  k_gate_ep<<<gE, 256, 0, stream>>>(GT, bg1, hid1, Xr8, D, 640, 64);

  // ---- layer 1 candidate ----
  gemm_diff8_c<<<gDc, 256, 0, stream>>>(S0q, Vq, Rq, Xr8, D, 640, 128, 64, Z2q);
  gemm_diff8w_c<<<gWc, 256, 0, stream>>>(S1q, Z2q, D, 640, 128, 64);
  gemm_dense<<<gDen, 256, 0, stream>>>(D, WTc1, CT, 640, 65536);
  k_cand_ep<<<gE, 256, 0, stream>>>(CT, GT, bc1, bg1, hid1, h1out, nullptr, nullptr, wp, bp, out);
}

// Round 11
// 536.458 us; speedup vs baseline: 1.1843x; 1.1843x over previous
//
#include <hip/hip_runtime.h>

typedef unsigned short u16;
typedef unsigned char u8;
typedef unsigned int u32;
typedef float f32x4 __attribute__((ext_vector_type(4)));
typedef __bf16 bf16x8 __attribute__((ext_vector_type(8)));
typedef int i32x8 __attribute__((ext_vector_type(8)));

// MX scale bytes (E8M0: 2^(b-127)): 0x77 = 2^-8 (operands quantized x256),
// 0x7F = 1.0 (X inputs).
#define SCL_A 0x77777777u
#define SCL_B1 0x7F7F7F7Fu
#define SCL_B256 0x77777777u

// ---------- helpers ----------
__device__ __forceinline__ u16 f2bf(float f){
  u32 u = __builtin_bit_cast(u32, f);
  u32 r = (u + 0x7fffu + ((u >> 16) & 1u)) >> 16;
  return (u16)r;
}
__device__ __forceinline__ float bf2f(u16 h){
  return __builtin_bit_cast(float, ((u32)h) << 16);
}
__device__ __forceinline__ u8 f2e4(float x){
  return (u8)(__builtin_amdgcn_cvt_pk_fp8_f32(x, x, 0, false) & 0xff);
}
__device__ __forceinline__ u32 pack4_e4(float a, float b, float c, float d){
  int w = __builtin_amdgcn_cvt_pk_fp8_f32(a, b, 0, false);
  w = __builtin_amdgcn_cvt_pk_fp8_f32(c, d, w, true);
  return (u32)w;
}
__device__ __forceinline__ void gl_lds16(const void* g, void* l){
  __builtin_amdgcn_global_load_lds((__attribute__((address_space(1))) void*)g,
                                   (__attribute__((address_space(3))) void*)l,
                                   16, 0, 0);
}
__device__ __forceinline__ float sigf(float x){ return 1.f/(1.f + __expf(-x)); }

// XCD-chunked block swizzle (T1). Requires nwg % 8 == 0 (all swizzled grids:
// 1152/1024/2048/512/256). Remap hw id -> contiguous logical chunk per XCD.
__device__ __forceinline__ void xcd_swizzle(int& x, int& y, int& z){
  int gx = gridDim.x, gy = gridDim.y;
  int nwg = gx * gy * gridDim.z;
  int lid = blockIdx.x + gx*(blockIdx.y + gy*blockIdx.z);
  int cpx = nwg >> 3;
  int swz = (lid & 7)*cpx + (lid >> 3);
  x = swz % gx;
  int rest = swz / gx;
  y = rest % gy;
  z = rest / gy;
}

// ---------- sums ----------
__global__ __launch_bounds__(256) void k_rowsum(const float* __restrict__ adj, float* __restrict__ inv_rs,
                                                float* __restrict__ cs){
  int j = blockIdx.x; int tid = threadIdx.x;
  float s = 0.f;
  for (int i = tid; i < 2048; i += 256) s += adj[(long)j*2048 + i];
  for (int off = 32; off; off >>= 1) s += __shfl_down(s, off, 64);
  __shared__ float red[4];
  if ((tid & 63) == 0) red[tid >> 6] = s;
  __syncthreads();
  if (tid == 0){
    float t = red[0] + red[1] + red[2] + red[3];
    inv_rs[j] = 1.f / fmaxf(t, 1e-8f);
    cs[j] = 0.f;   // zero for k_colsum2's atomics (stream-ordered after this kernel)
  }
}

__global__ __launch_bounds__(256) void k_colsum2(const float* __restrict__ adj, float* __restrict__ cs){
  int j0 = blockIdx.x * 64, i0 = blockIdx.y * 128;
  int jj = threadIdx.x & 63, w = threadIdx.x >> 6;
  float s = 0.f;
  for (int i = w; i < 128; i += 4) s += adj[(long)(i0+i)*2048 + j0 + jj];
  __shared__ float red[256];
  red[threadIdx.x] = s;
  __syncthreads();
  if (w == 0){
    float t = red[jj] + red[64+jj] + red[128+jj] + red[192+jj];
    atomicAdd(&cs[j0+jj], t);
  }
}

// Merged S-build: one adj tile read ->
//   S0Tq[j][i] = e4m3(adj[j][i]*inv_rs[j] x256)   (= S0^T row-major, fp8)
//   S1q [j][i] = e4m3(adj[j][i]/max(cs[i]) x256)  (= S1 row-major, fp8)
//   S0  [i][j] = bf16(adj[j][i]*inv_rs[j]), S0q = e4m3(S0 x256)  (LDS transpose)
__global__ __launch_bounds__(256) void k_build_S(const float* __restrict__ adj,
                                                 const float* __restrict__ inv_rs,
                                                 const float* __restrict__ cs,
                                                 u16* __restrict__ S0, u8* __restrict__ S0q,
                                                 u8* __restrict__ S0Tq, u8* __restrict__ S1q){
  __shared__ float t[64*66];
  __shared__ float rsl[64];
  __shared__ float icl[64];
  int i0 = blockIdx.x * 64, j0 = blockIdx.y * 64;
  int tid = threadIdx.x;
  if (tid < 64) rsl[tid] = inv_rs[j0 + tid];
  else if (tid >= 64 && tid < 128) icl[tid-64] = 1.f / fmaxf(cs[i0 + tid-64], 1e-8f);
  __syncthreads();
  for (int e = tid; e < 4096; e += 256){
    int jj = e >> 6, ii = e & 63;                 // lane varies ii: adj read + fp8 writes coalesced
    float a = adj[(long)(j0+jj)*2048 + i0 + ii];
    t[jj*66 + ii] = a;
    long o = (long)(j0+jj)*2048 + i0 + ii;
    S0Tq[o] = f2e4(a * rsl[jj] * 256.f);
    S1q[o]  = f2e4(a * icl[ii] * 256.f);
  }
  __syncthreads();
  for (int e = tid; e < 4096; e += 256){
    int ii = e >> 6, jj = e & 63;                 // lane varies jj: S0/S0q writes coalesced
    u16 vb = f2bf(t[jj*66 + ii] * rsl[jj]);       // LDS stride 66: 2-way bank alias (free, m136)
    long o = (long)(i0+ii)*2048 + j0 + jj;
    S0[o] = vb;
    S0q[o] = f2e4(bf2f(vb)*256.f);
  }
}

// Merged weight pack: z selects {wg0,wc0,wg1,wc1}. WT[o][k]=w[(f*5+m)*OUTr+o],
// k=(m,f) with per-z (OUTr,F,Fp,Kd); zero-padded.
__global__ __launch_bounds__(256) void k_packW4(const float* __restrict__ wg0, const float* __restrict__ wc0,
                                                const float* __restrict__ wg1, const float* __restrict__ wc1,
                                                u16* __restrict__ WTg0, u16* __restrict__ WTc0,
                                                u16* __restrict__ WTg1, u16* __restrict__ WTc1){
  int z = blockIdx.y;
  const float* w = (z==0) ? wg0 : (z==1) ? wc0 : (z==2) ? wg1 : wc1;
  u16* WT       = (z==0) ? WTg0 : (z==1) ? WTc0 : (z==2) ? WTg1 : WTc1;
  int OUTr = (z==0 || z==2) ? 128 : 64;
  int F  = (z < 2) ? 65 : 128;
  int Fp = (z < 2) ? 72 : 128;
  int Kd = (z < 2) ? 384 : 640;
  int idx = blockIdx.x*256 + threadIdx.x;
  if (idx >= 128*Kd) return;
  int o = idx / Kd, k = idx - o*Kd;
  int m = k / Fp, f = k - m*Fp;
  float v = 0.f;
  if (o < OUTr && m < 5 && f < F) v = w[(long)(f*5 + m)*OUTr + o];
  WT[idx] = f2bf(v);
}

// hidden (f32) -> fp8 X0T rows (b, rowoff+u) + bf16 D cols (coloff+u); layer-0 extras: inp + pads
__global__ __launch_bounds__(256) void k_hx_build(const float* __restrict__ hx, const float* __restrict__ inp,
                                                  u8* __restrict__ X0T, u16* __restrict__ D,
                                                  int Fp, int rowoff, long ldD, int coloff, int l0extras){
  __shared__ float t[64*66];
  int b = blockIdx.x, n0 = blockIdx.y * 64;
  int tid = threadIdx.x;
  const float* hb = hx + (long)b*2048*64;
  long bn0 = (long)b*2048 + n0;
  for (int e = tid; e < 4096; e += 256){
    int u = e & 63, ni = e >> 6;            // lane->u: f32 read coalesced
    t[ni*66 + u] = hb[(long)(n0+ni)*64 + u];
  }
  __syncthreads();
  for (int e = tid; e < 4096; e += 256){
    int u = e >> 6, ni = e & 63;            // lane->ni: fp8 row write coalesced
    X0T[((long)b*Fp + rowoff + u)*2048 + n0 + ni] = f2e4(t[ni*66 + u]);
  }
  for (int e = tid; e < 4096; e += 256){
    int ni = e >> 6, u = e & 63;            // lane->u: D col write coalesced
    D[(bn0 + ni)*ldD + coloff + u] = f2bf(t[ni*66 + u]);
  }
  if (l0extras){
    if (tid < 64){
      float v = inp[(long)b*2048 + n0 + tid];
      X0T[((long)b*Fp)*2048 + n0 + tid] = f2e4(v);
      D[(bn0 + tid)*ldD] = f2bf(v);
    }
    for (int e = tid; e < 7*64; e += 256){
      int f = 65 + (e >> 6), ni = e & 63;
      X0T[((long)b*Fp + f)*2048 + n0 + ni] = 0;
    }
    for (int e = tid; e < 64*31; e += 256){
      int ni = e / 31, wc = e - ni*31;
      int col = (wc < 7) ? (65 + wc) : (353 + wc);   // {65..71, 360..383}
      D[(bn0 + ni)*ldD + col] = 0;
    }
  }
}

// ---------- bf16 GEMM core, BK=64 (dense) ----------
__device__ __forceinline__ void gemm_core(const u16* __restrict__ A, const u16* __restrict__ Bt,
                                          int K, long tM, long tC,
                                          u16* lA, u16* lB, f32x4 (&acc)[4][4]){
  int tid = threadIdx.x;
  int wv = tid >> 6, lane = tid & 63;
  int q = lane >> 4, r16 = lane & 15;

  const u16* ga[4]; const u16* gb[4];
  u16* la[4]; u16* lb[4];
  #pragma unroll
  for (int it = 0; it < 4; it++){
    int L = it*256 + tid;
    int r = L >> 3, g = (L & 7) ^ (r & 7);
    ga[it] = A  + (tM + r)*(long)K + g*8;
    gb[it] = Bt + (tC + r)*(long)K + g*8;
    la[it] = lA + (it*256 + wv*64)*8;
    lb[it] = lB + (it*256 + wv*64)*8;
  }

  #pragma unroll
  for (int i = 0; i < 4; i++)
    #pragma unroll
    for (int j = 0; j < 4; j++){ acc[i][j][0]=0.f; acc[i][j][1]=0.f; acc[i][j][2]=0.f; acc[i][j][3]=0.f; }

  int wm = wv & 1, wn = wv >> 1;
  int aoff[4][2], boff[4][2];
  #pragma unroll
  for (int s = 0; s < 4; s++){
    int m = wm*64 + s*16 + r16;
    int n = wn*64 + s*16 + r16;
    #pragma unroll
    for (int h = 0; h < 2; h++){
      aoff[s][h] = (m*8 + ((h*4 + q) ^ (m & 7))) * 8;
      boff[s][h] = (n*8 + ((h*4 + q) ^ (n & 7))) * 8;
    }
  }

  for (int k0 = 0; k0 < K; k0 += 64){
    __syncthreads();
    #pragma unroll
    for (int it = 0; it < 4; it++){
      gl_lds16(ga[it] + k0, la[it]);
      gl_lds16(gb[it] + k0, lb[it]);
    }
    asm volatile("s_waitcnt vmcnt(0)" ::: "memory");
    __syncthreads();
    #pragma unroll
    for (int h = 0; h < 2; h++){
      bf16x8 af[4], bfr[4];
      #pragma unroll
      for (int s = 0; s < 4; s++){
        af[s]  = *(const bf16x8*)&lA[aoff[s][h]];
        bfr[s] = *(const bf16x8*)&lB[boff[s][h]];
      }
      #pragma unroll
      for (int i = 0; i < 4; i++)
        #pragma unroll
        for (int j = 0; j < 4; j++)
          acc[i][j] = __builtin_amdgcn_mfma_f32_16x16x32_bf16(af[i], bfr[j], acc[i][j], 0, 0, 0);
    }
  }
}

// ---------- fp8 MX GEMM core, BK=128 bytes ----------
// Storage permutation sigma(g) = (g>>1)|((g&1)<<2): frag-read slot pattern
// (e*4+q)^(m&7), measured SQ_LDS_BANK_CONFLICT = 0. SCLB: B-operand MX scale.
template<u32 SCLB>
__device__ __forceinline__ void gemm_core8(const u8* __restrict__ A, const u8* __restrict__ Bt,
                                           int K, long tM, long tC,
                                           u8* lA, u8* lB, f32x4 (&acc)[4][4]){
  int tid = threadIdx.x;
  int wv = tid >> 6, lane = tid & 63;
  int q = lane >> 4, r16 = lane & 15;

  const u8* ga[4]; const u8* gb[4];
  u8* la[4]; u8* lb[4];
  #pragma unroll
  for (int it = 0; it < 4; it++){
    int L = it*256 + tid;
    int r = L >> 3, x = (L & 7) ^ (r & 7);
    int g = ((x & 3) << 1) | (x >> 2);     // sigma^-1
    ga[it] = A  + (tM + r)*(long)K + g*16;
    gb[it] = Bt + (tC + r)*(long)K + g*16;
    la[it] = lA + (it*256 + wv*64)*16;
    lb[it] = lB + (it*256 + wv*64)*16;
  }

  #pragma unroll
  for (int i = 0; i < 4; i++)
    #pragma unroll
    for (int j = 0; j < 4; j++){ acc[i][j][0]=0.f; acc[i][j][1]=0.f; acc[i][j][2]=0.f; acc[i][j][3]=0.f; }

  int wm = wv & 1, wn = wv >> 1;
  int aoff[4][2], boff[4][2];
  #pragma unroll
  for (int s = 0; s < 4; s++){
    int m = wm*64 + s*16 + r16;
    int n = wn*64 + s*16 + r16;
    #pragma unroll
    for (int e = 0; e < 2; e++){
      aoff[s][e] = m*128 + ((e*4 + q) ^ (m & 7)) * 16;
      boff[s][e] = n*128 + ((e*4 + q) ^ (n & 7)) * 16;
    }
  }

  for (int k0 = 0; k0 < K; k0 += 128){
    __syncthreads();
    #pragma unroll
    for (int it = 0; it < 4; it++){
      gl_lds16(ga[it] + k0, la[it]);
      gl_lds16(gb[it] + k0, lb[it]);
    }
    asm volatile("s_waitcnt vmcnt(0)" ::: "memory");
    __syncthreads();
    i32x8 af[4], bfr[4];
    #pragma unroll
    for (int s = 0; s < 4; s++){
      uint4 a0 = *(const uint4*)&lA[aoff[s][0]];
      uint4 a1 = *(const uint4*)&lA[aoff[s][1]];
      i32x8 av; av[0]=a0.x; av[1]=a0.y; av[2]=a0.z; av[3]=a0.w; av[4]=a1.x; av[5]=a1.y; av[6]=a1.z; av[7]=a1.w;
      af[s] = av;
      uint4 b0 = *(const uint4*)&lB[boff[s][0]];
      uint4 b1 = *(const uint4*)&lB[boff[s][1]];
      i32x8 bv; bv[0]=b0.x; bv[1]=b0.y; bv[2]=b0.z; bv[3]=b0.w; bv[4]=b1.x; bv[5]=b1.y; bv[6]=b1.z; bv[7]=b1.w;
      bfr[s] = bv;
    }
    #pragma unroll
    for (int i = 0; i < 4; i++)
      #pragma unroll
      for (int j = 0; j < 4; j++)
        acc[i][j] = __builtin_amdgcn_mfma_scale_f32_16x16x128_f8f6f4(
                      af[i], bfr[j], acc[i][j], 0, 0, 0, SCL_A, 0, SCLB);
  }
}

// ---------- fp8 precompute: bz=0: R=S1@S0 -> Rq + RTq; bz=1: V=2*S0^2-I -> Vq ----------
// A=S0Tq ([gi][k]=S0[k][gi] x256), Bt=S1q/S0q (x256) -> acc[gi][gc] = (S1@S0)[gc][gi] / (S0^2)[gc][gi].
__global__ __launch_bounds__(256) void gemm_pre8(const u8* __restrict__ S0Tq, const u8* __restrict__ S1q,
                                                 const u8* __restrict__ S0q,
                                                 u8* __restrict__ Rq, u8* __restrict__ RTq, u8* __restrict__ Vq){
  __shared__ u8 lA[16384];
  __shared__ u8 lB[16384];
  f32x4 acc[4][4];
  int bx, by, bz;
  xcd_swizzle(bx, by, bz);
  const u8* Bt = (bz == 0) ? S1q : S0q;
  long tM = (long)bx * 128, tC = (long)by * 128;
  gemm_core8<SCL_B256>(S0Tq, Bt, 2048, tM, tC, lA, lB, acc);

  int tid = threadIdx.x, wv = tid >> 6, lane = tid & 63;
  int q = lane >> 4, r16 = lane & 15, wm = wv & 1, wn = wv >> 1;
  #pragma unroll
  for (int i = 0; i < 4; i++){
    long gi = tM + wm*64 + i*16 + q*4;
    #pragma unroll
    for (int j = 0; j < 4; j++){
      long gc = tC + wn*64 + j*16 + r16;
      f32x4 v = acc[i][j];
      if (bz == 0){
        // v[r] = R[gc][gi+r]; Rq row-major R; RTq row-major R^T (A-operand for gemm_w8)
        *(u32*)(Rq + gc*2048 + gi) = pack4_e4(v[0]*256.f, v[1]*256.f, v[2]*256.f, v[3]*256.f);
        RTq[(gi+0)*2048 + gc] = f2e4(v[0]*256.f);
        RTq[(gi+1)*2048 + gc] = f2e4(v[1]*256.f);
        RTq[(gi+2)*2048 + gc] = f2e4(v[2]*256.f);
        RTq[(gi+3)*2048 + gc] = f2e4(v[3]*256.f);
      } else {
        float x0 = 2.f*v[0] - ((gi+0) == gc ? 1.f : 0.f);
        float x1 = 2.f*v[1] - ((gi+1) == gc ? 1.f : 0.f);
        float x2 = 2.f*v[2] - ((gi+2) == gc ? 1.f : 0.f);
        float x3 = 2.f*v[3] - ((gi+3) == gc ? 1.f : 0.f);
        *(u32*)(Vq + gc*2048 + gi) = pack4_e4(x0*256.f, x1*256.f, x2*256.f, x3*256.f);
      }
    }
  }
}

// ---------- fp8 precompute: W = 2*S1@R - S0 -> Wq ----------
// A=RTq ([gi][k]=R[k][gi] x256), Bt=S1q (x256) -> acc = (S1@R)[gc][gi]; S0 read bf16.
__global__ __launch_bounds__(256) void gemm_w8(const u8* __restrict__ RTq, const u8* __restrict__ S1q,
                                               const u16* __restrict__ S0, u8* __restrict__ Wq){
  __shared__ u8 lA[16384];
  __shared__ u8 lB[16384];
  f32x4 acc[4][4];
  int bx, by, bz;
  xcd_swizzle(bx, by, bz);
  long tM = (long)bx * 128, tC = (long)by * 128;
  gemm_core8<SCL_B256>(RTq, S1q, 2048, tM, tC, lA, lB, acc);

  int tid = threadIdx.x, wv = tid >> 6, lane = tid & 63;
  int q = lane >> 4, r16 = lane & 15, wm = wv & 1, wn = wv >> 1;
  #pragma unroll
  for (int i = 0; i < 4; i++){
    long gi = tM + wm*64 + i*16 + q*4;
    #pragma unroll
    for (int j = 0; j < 4; j++){
      long gc = tC + wn*64 + j*16 + r16;
      f32x4 v = acc[i][j];
      ushort4 x0 = *(const ushort4*)(S0 + gc*2048 + gi);
      *(u32*)(Wq + gc*2048 + gi) = pack4_e4((2.f*v[0] - bf2f(x0.x))*256.f,
                                            (2.f*v[1] - bf2f(x0.y))*256.f,
                                            (2.f*v[2] - bf2f(x0.z))*256.f,
                                            (2.f*v[3] - bf2f(x0.w))*256.f);
    }
  }
}

// ---------- fp8 batched diffusion (gate): z selects {S0,V,R,W}; writes D slice z+1 ----------
template<int FP>
__global__ __launch_bounds__(256) void gemm_diff8(const u8* __restrict__ M0, const u8* __restrict__ M1,
                                                  const u8* __restrict__ M2, const u8* __restrict__ M3,
                                                  const u8* __restrict__ X, u16* __restrict__ D, long ldD){
  __shared__ u8 lA[16384];
  __shared__ u8 lB[16384];
  f32x4 acc[4][4];
  int bx, by, z;
  xcd_swizzle(bx, by, z);
  const u8* A = (z == 0) ? M0 : (z == 1) ? M1 : (z == 2) ? M2 : M3;
  long tM = (long)bx * 128, tC = (long)by * 128;
  gemm_core8<SCL_B1>(A, X, 2048, tM, tC, lA, lB, acc);

  int tid = threadIdx.x, wv = tid >> 6, lane = tid & 63;
  int q = lane >> 4, r16 = lane & 15, wm = wv & 1, wn = wv >> 1;
  int zb = (z + 1) * FP;
  #pragma unroll
  for (int i = 0; i < 4; i++){
    long gi = tM + wm*64 + i*16 + q*4;
    #pragma unroll
    for (int j = 0; j < 4; j++){
      int gc = (int)(tC + wn*64 + j*16 + r16);
      int b = gc / FP, f = gc - b*FP;
      long rb = (long)b*2048 + gi;
      f32x4 v = acc[i][j];
      D[(rb+0)*ldD + zb + f] = f2bf(v[0]);
      D[(rb+1)*ldD + zb + f] = f2bf(v[1]);
      D[(rb+2)*ldD + zb + f] = f2bf(v[2]);
      D[(rb+3)*ldD + zb + f] = f2bf(v[3]);
    }
  }
}

// ---------- fp8 candidate diffusion: Xr (2048 x 2048), writes D col (z+1)*Fp+fin+u ----------
__global__ __launch_bounds__(256) void gemm_diff8_c(const u8* __restrict__ M0, const u8* __restrict__ M1,
                                                    const u8* __restrict__ M2, const u8* __restrict__ M3,
                                                    const u8* __restrict__ Xr, u16* __restrict__ D,
                                                    long ldD, int Fp, int fin){
  __shared__ u8 lA[16384];
  __shared__ u8 lB[16384];
  f32x4 acc[4][4];
  int bx, by, z;
  xcd_swizzle(bx, by, z);
  const u8* A = (z == 0) ? M0 : (z == 1) ? M1 : (z == 2) ? M2 : M3;
  long tM = (long)bx * 128, tC = (long)by * 128;
  gemm_core8<SCL_B1>(A, Xr, 2048, tM, tC, lA, lB, acc);

  int tid = threadIdx.x, wv = tid >> 6, lane = tid & 63;
  int q = lane >> 4, r16 = lane & 15, wm = wv & 1, wn = wv >> 1;
  int zb = (z + 1) * Fp + fin;
  #pragma unroll
  for (int i = 0; i < 4; i++){
    long gi = tM + wm*64 + i*16 + q*4;
    #pragma unroll
    for (int j = 0; j < 4; j++){
      int gc = (int)(tC + wn*64 + j*16 + r16);
      int b = gc >> 6, u = gc & 63;
      long rb = (long)b*2048 + gi;
      f32x4 v = acc[i][j];
      D[(rb+0)*ldD + zb + u] = f2bf(v[0]);
      D[(rb+1)*ldD + zb + u] = f2bf(v[1]);
      D[(rb+2)*ldD + zb + u] = f2bf(v[2]);
      D[(rb+3)*ldD + zb + u] = f2bf(v[3]);
    }
  }
}

// ---------- dense (bf16): OutT[c][i] = bf16( sum_k A[i,k]*Bt[c,k] ) ----------
__global__ __launch_bounds__(256) void gemm_dense(const u16* __restrict__ A, const u16* __restrict__ Bt,
                                                  u16* __restrict__ Out, int K, long ldOut){
  __shared__ u16 lA[8192];
  __shared__ u16 lB[8192];
  f32x4 acc[4][4];
  long tM = (long)blockIdx.x * 128, tC = (long)blockIdx.y * 128;
  gemm_core(A, Bt, K, tM, tC, lA, lB, acc);

  int tid = threadIdx.x, wv = tid >> 6, lane = tid & 63;
  int q = lane >> 4, r16 = lane & 15, wm = wv & 1, wn = wv >> 1;
  #pragma unroll
  for (int i = 0; i < 4; i++){
    long gi = tM + wm*64 + i*16 + q*4;
    #pragma unroll
    for (int j = 0; j < 4; j++){
      long gc = tC + wn*64 + j*16 + r16;
      f32x4 v = acc[i][j];
      ushort4 o;
      o.x = f2bf(v[0]); o.y = f2bf(v[1]); o.z = f2bf(v[2]); o.w = f2bf(v[3]);
      *(ushort4*)(Out + gc*ldOut + gi) = o;
    }
  }
}

// ---------- GRU epilogues ----------
__global__ __launch_bounds__(256) void k_gate_ep(const u16* __restrict__ GT, const float* __restrict__ bg,
                                                 const float* __restrict__ hid, u8* __restrict__ Xr8,
                                                 u16* __restrict__ D, long ldD, int coloff){
  __shared__ float t[64*66];
  __shared__ u16 tb[64*66];
  int b = blockIdx.x, n0 = blockIdx.y * 64;
  int tid = threadIdx.x;
  long bn0 = (long)b*2048 + n0;
  for (int e = tid; e < 4096; e += 256){
    int u = e & 63, ni = e >> 6;            // lane->u: f32 hid read coalesced
    t[ni*66 + u] = hid[(bn0 + ni)*64 + u];
  }
  __syncthreads();
  for (int e = tid; e < 4096; e += 256){
    int u = e >> 6, ni = e & 63;            // lane->ni: GT read + Xr8 write coalesced
    float r = sigf(bf2f(GT[(long)u*65536 + bn0 + ni]) + bg[u]);
    float pv = r * t[ni*66 + u];
    Xr8[((long)b*64 + u)*2048 + n0 + ni] = f2e4(pv);
    tb[ni*66 + u] = f2bf(pv);
  }
  __syncthreads();
  for (int e = tid; e < 4096; e += 256){
    int ni = e >> 6, u = e & 63;            // lane->u: D col write coalesced
    D[(bn0 + ni)*ldD + coloff + u] = tb[ni*66 + u];
  }
}

__global__ __launch_bounds__(256) void k_cand_ep(const u16* __restrict__ CT, const u16* __restrict__ GT,
                                                 const float* __restrict__ bc, const float* __restrict__ bg,
                                                 const float* __restrict__ hx, float* __restrict__ hout,
                                                 u8* __restrict__ X0T_next, u16* __restrict__ Dnext,
                                                 const float* __restrict__ wproj, const float* __restrict__ bproj,
                                                 float* __restrict__ out){
  __shared__ u16 tc[64*66];
  __shared__ u16 tu[64*66];
  __shared__ u16 th[64*66];
  int b = blockIdx.x, n0 = blockIdx.y * 64;
  int tid = threadIdx.x;
  long bn0 = (long)b*2048 + n0;
  for (int e = tid; e < 4096; e += 256){
    int u = e >> 6, ni = e & 63;
    float cv = tanhf(bf2f(CT[(long)u*65536 + bn0 + ni]) + bc[u]);
    float uv = sigf(bf2f(GT[(long)(64+u)*65536 + bn0 + ni]) + bg[64+u]);
    tc[ni*66 + u] = f2bf(cv);
    tu[ni*66 + u] = f2bf(uv);
  }
  __syncthreads();
  int lane = tid & 63, wv = tid >> 6;
  for (int it = 0; it < 16; ++it){
    int ni = it*4 + wv, u = lane;
    float hxv = hx[(bn0 + ni)*64 + u];
    float uv = bf2f(tu[ni*66 + u]), cv = bf2f(tc[ni*66 + u]);
    float h = uv*hxv + (1.f - uv)*cv;
    hout[(bn0 + ni)*64 + u] = h;
    if (Dnext) Dnext[(bn0 + ni)*640 + u] = f2bf(h);
    th[ni*66 + u] = f2bf(h);
    if (wproj){
      float v = h * wproj[u];
      for (int off = 32; off; off >>= 1) v += __shfl_down(v, off, 64);
      if (lane == 0) out[(long)b*2048 + n0 + ni] = v + bproj[0];
    }
  }
  __syncthreads();
  if (X0T_next){
    for (int e = tid; e < 4096; e += 256){
      int u = e >> 6, ni = e & 63;          // lane->ni: fp8 row write coalesced
      X0T_next[((long)b*128 + u)*2048 + n0 + ni] = f2e4(bf2f(th[ni*66 + u]));
    }
  }
}

// ---------- launch ----------
extern "C" void kernel_launch(void* const* d_in, const int* in_sizes, int n_in,
                              void* d_out, int out_size, void* d_ws, size_t ws_size,
                              hipStream_t stream){
  (void)in_sizes; (void)n_in; (void)out_size; (void)ws_size;
  const float* inputs = (const float*)d_in[0];
  const float* hidden = (const float*)d_in[1];
  const float* adj    = (const float*)d_in[2];
  const float* wg0 = (const float*)d_in[3];
  const float* bg0 = (const float*)d_in[4];
  const float* wc0 = (const float*)d_in[5];
  const float* bc0 = (const float*)d_in[6];
  const float* wg1 = (const float*)d_in[7];
  const float* bg1 = (const float*)d_in[8];
  const float* wc1 = (const float*)d_in[9];
  const float* bc1 = (const float*)d_in[10];
  const float* wp  = (const float*)d_in[11];
  const float* bp  = (const float*)d_in[12];
  float* out = (float*)d_out;

  char* p = (char*)d_ws;
  auto alloc = [&](size_t bytes)->char*{ char* r = p; p += (bytes + 255) & ~(size_t)255; return r; };
  float* inv_rs = (float*)alloc(2048*4);
  float* cs     = (float*)alloc(2048*4);
  const size_t SB  = (size_t)2048*2048*2;   // bf16 NxN
  const size_t SB8 = (size_t)2048*2048;     // fp8 NxN
  u16* S0  = (u16*)alloc(SB);
  u8*  S0q = (u8*)alloc(SB8);
  u8*  S0Tq= (u8*)alloc(SB8);
  u8*  S1q = (u8*)alloc(SB8);
  u8*  Rq  = (u8*)alloc(SB8);
  u8*  RTq = (u8*)alloc(SB8);
  u8*  Vq  = (u8*)alloc(SB8);
  u8*  Wq  = (u8*)alloc(SB8);
  u8*  X0a8 = (u8*)alloc((size_t)2304*2048); // layer0 cat, fp8, Fp=72
  u8*  X0b8 = (u8*)alloc((size_t)4096*2048); // layer1 cat, fp8, Fp=128
  u8*  Xr8  = (u8*)alloc(SB8);               // r*hx, fp8
  u16* D   = (u16*)alloc((size_t)65536*640*2);
  u16* GT = (u16*)alloc((size_t)128*65536*2);
  u16* CT = (u16*)alloc((size_t)128*65536*2);
  u16* WTg0 = (u16*)alloc((size_t)128*384*2);
  u16* WTc0 = (u16*)alloc((size_t)128*384*2);
  u16* WTg1 = (u16*)alloc((size_t)128*640*2);
  u16* WTc1 = (u16*)alloc((size_t)128*640*2);

  const float* hid0 = hidden;
  const float* hid1 = hidden + (size_t)4194304;
  float* h0out = out + 65536;
  float* h1out = out + 65536 + 4194304;

  // ---- setup ----
  k_rowsum<<<2048, 256, 0, stream>>>(adj, inv_rs, cs);
  k_colsum2<<<dim3(32,16), 256, 0, stream>>>(adj, cs);
  k_build_S<<<dim3(32,32), 256, 0, stream>>>(adj, inv_rs, cs, S0, S0q, S0Tq, S1q);
  k_packW4<<<dim3(320,4), 256, 0, stream>>>(wg0, wc0, wg1, wc1, WTg0, WTc0, WTg1, WTc1);
  k_hx_build<<<dim3(32,32), 256, 0, stream>>>(hid0, inputs, X0a8, D, 72, 1, 384, 1, 1);

  // ---- precompute diffusion operators R, V, W (fp8 MX compute) ----
  gemm_pre8<<<dim3(16,16,2), 256, 0, stream>>>(S0Tq, S1q, S0q, Rq, RTq, Vq);
  gemm_w8  <<<dim3(16,16),   256, 0, stream>>>(RTq, S1q, S0, Wq);

  dim3 gD0(16, 18, 4), gD1(16, 32, 4), gDc(16, 16, 4), gDen(512, 1), gE(32, 32);

  // ---- layer 0 gate ----
  gemm_diff8<72><<<gD0, 256, 0, stream>>>(S0q, Vq, Rq, Wq, X0a8, D, 384);
  gemm_dense<<<gDen, 256, 0, stream>>>(D, WTg0, GT, 384, 65536);
  k_gate_ep<<<gE, 256, 0, stream>>>(GT, bg0, hid0, Xr8, D, 384, 1);

  // ---- layer 0 candidate (diffuse only r*hx; inp cols reused from gate pass) ----
  gemm_diff8_c<<<gDc, 256, 0, stream>>>(S0q, Vq, Rq, Wq, Xr8, D, 384, 72, 1);
  gemm_dense<<<gDen, 256, 0, stream>>>(D, WTc0, CT, 384, 65536);
  k_cand_ep<<<gE, 256, 0, stream>>>(CT, GT, bc0, bg0, hid0, h0out, X0b8, D, nullptr, nullptr, nullptr);

  // ---- layer 1 build ----
  k_hx_build<<<dim3(32,32), 256, 0, stream>>>(hid1, nullptr, X0b8, D, 128, 64, 640, 64, 0);

  // ---- layer 1 gate ----
  gemm_diff8<128><<<gD1, 256, 0, stream>>>(S0q, Vq, Rq, Wq, X0b8, D, 640);
  gemm_dense<<<gDen, 256, 0, stream>>>(D, WTg1, GT, 640, 65536);
  k_gate_ep<<<gE, 256, 0, stream>>>(GT, bg1, hid1, Xr8, D, 640, 64);

  // ---- layer 1 candidate ----
  gemm_diff8_c<<<gDc, 256, 0, stream>>>(S0q, Vq, Rq, Wq, Xr8, D, 640, 128, 64);
  gemm_dense<<<gDen, 256, 0, stream>>>(D, WTc1, CT, 640, 65536);
  k_cand_ep<<<gE, 256, 0, stream>>>(CT, GT, bc1, bg1, hid1, h1out, nullptr, nullptr, wp, bp, out);
}

// Round 12
// 531.407 us; speedup vs baseline: 1.1956x; 1.0095x over previous
//
#include <hip/hip_runtime.h>

typedef unsigned short u16;
typedef unsigned char u8;
typedef unsigned int u32;
typedef float f32x4 __attribute__((ext_vector_type(4)));
typedef __bf16 bf16x8 __attribute__((ext_vector_type(8)));
typedef int i32x8 __attribute__((ext_vector_type(8)));

// MX scale bytes (E8M0: 2^(b-127)): 0x77 = 2^-8 (operands quantized x256),
// 0x7F = 1.0 (X inputs).
#define SCL_A 0x77777777u
#define SCL_B1 0x7F7F7F7Fu
#define SCL_B256 0x77777777u

// ---------- helpers ----------
__device__ __forceinline__ u16 f2bf(float f){
  u32 u = __builtin_bit_cast(u32, f);
  u32 r = (u + 0x7fffu + ((u >> 16) & 1u)) >> 16;
  return (u16)r;
}
__device__ __forceinline__ float bf2f(u16 h){
  return __builtin_bit_cast(float, ((u32)h) << 16);
}
__device__ __forceinline__ u8 f2e4(float x){
  return (u8)(__builtin_amdgcn_cvt_pk_fp8_f32(x, x, 0, false) & 0xff);
}
__device__ __forceinline__ u32 pack4_e4(float a, float b, float c, float d){
  int w = __builtin_amdgcn_cvt_pk_fp8_f32(a, b, 0, false);
  w = __builtin_amdgcn_cvt_pk_fp8_f32(c, d, w, true);
  return (u32)w;
}
__device__ __forceinline__ void gl_lds16(const void* g, void* l){
  __builtin_amdgcn_global_load_lds((__attribute__((address_space(1))) void*)g,
                                   (__attribute__((address_space(3))) void*)l,
                                   16, 0, 0);
}
__device__ __forceinline__ float sigf(float x){ return 1.f/(1.f + __expf(-x)); }

// XCD-chunked block swizzle (T1). Requires nwg % 8 == 0 (all swizzled grids:
// 1152/1024/2048/512/256). Remap hw id -> contiguous logical chunk per XCD.
__device__ __forceinline__ void xcd_swizzle(int& x, int& y, int& z){
  int gx = gridDim.x, gy = gridDim.y;
  int nwg = gx * gy * gridDim.z;
  int lid = blockIdx.x + gx*(blockIdx.y + gy*blockIdx.z);
  int cpx = nwg >> 3;
  int swz = (lid & 7)*cpx + (lid >> 3);
  x = swz % gx;
  int rest = swz / gx;
  y = rest % gy;
  z = rest / gy;
}

// ---------- sums ----------
__global__ __launch_bounds__(256) void k_rowsum(const float* __restrict__ adj, float* __restrict__ inv_rs,
                                                float* __restrict__ cs){
  int j = blockIdx.x; int tid = threadIdx.x;
  float s = 0.f;
  for (int i = tid; i < 2048; i += 256) s += adj[(long)j*2048 + i];
  for (int off = 32; off; off >>= 1) s += __shfl_down(s, off, 64);
  __shared__ float red[4];
  if ((tid & 63) == 0) red[tid >> 6] = s;
  __syncthreads();
  if (tid == 0){
    float t = red[0] + red[1] + red[2] + red[3];
    inv_rs[j] = 1.f / fmaxf(t, 1e-8f);
    cs[j] = 0.f;   // zero for k_colsum2's atomics (stream-ordered after this kernel)
  }
}

__global__ __launch_bounds__(256) void k_colsum2(const float* __restrict__ adj, float* __restrict__ cs){
  int j0 = blockIdx.x * 64, i0 = blockIdx.y * 128;
  int jj = threadIdx.x & 63, w = threadIdx.x >> 6;
  float s = 0.f;
  for (int i = w; i < 128; i += 4) s += adj[(long)(i0+i)*2048 + j0 + jj];
  __shared__ float red[256];
  red[threadIdx.x] = s;
  __syncthreads();
  if (w == 0){
    float t = red[jj] + red[64+jj] + red[128+jj] + red[192+jj];
    atomicAdd(&cs[j0+jj], t);
  }
}

// Merged S-build: one adj tile read ->
//   S0Tq[j][i] = e4m3(adj[j][i]*inv_rs[j] x256)   (= S0^T row-major, fp8)
//   S1q [j][i] = e4m3(adj[j][i]/max(cs[i]) x256)  (= S1 row-major, fp8)
//   S0  [i][j] = bf16(adj[j][i]*inv_rs[j]), S0q = e4m3(S0 x256)  (LDS transpose)
__global__ __launch_bounds__(256) void k_build_S(const float* __restrict__ adj,
                                                 const float* __restrict__ inv_rs,
                                                 const float* __restrict__ cs,
                                                 u16* __restrict__ S0, u8* __restrict__ S0q,
                                                 u8* __restrict__ S0Tq, u8* __restrict__ S1q){
  __shared__ float t[64*66];
  __shared__ float rsl[64];
  __shared__ float icl[64];
  int i0 = blockIdx.x * 64, j0 = blockIdx.y * 64;
  int tid = threadIdx.x;
  if (tid < 64) rsl[tid] = inv_rs[j0 + tid];
  else if (tid >= 64 && tid < 128) icl[tid-64] = 1.f / fmaxf(cs[i0 + tid-64], 1e-8f);
  __syncthreads();
  for (int e = tid; e < 4096; e += 256){
    int jj = e >> 6, ii = e & 63;                 // lane varies ii: adj read + fp8 writes coalesced
    float a = adj[(long)(j0+jj)*2048 + i0 + ii];
    t[jj*66 + ii] = a;
    long o = (long)(j0+jj)*2048 + i0 + ii;
    S0Tq[o] = f2e4(a * rsl[jj] * 256.f);
    S1q[o]  = f2e4(a * icl[ii] * 256.f);
  }
  __syncthreads();
  for (int e = tid; e < 4096; e += 256){
    int ii = e >> 6, jj = e & 63;                 // lane varies jj: S0/S0q writes coalesced
    u16 vb = f2bf(t[jj*66 + ii] * rsl[jj]);       // LDS stride 66: 2-way bank alias (free, m136)
    long o = (long)(i0+ii)*2048 + j0 + jj;
    S0[o] = vb;
    S0q[o] = f2e4(bf2f(vb)*256.f);
  }
}

// Merged weight pack: z selects {wg0,wc0,wg1,wc1}. WT[o][k]=w[(f*5+m)*OUTr+o],
// k=(m,f) with per-z (OUTr,F,Fp,Kd); zero-padded.
__global__ __launch_bounds__(256) void k_packW4(const float* __restrict__ wg0, const float* __restrict__ wc0,
                                                const float* __restrict__ wg1, const float* __restrict__ wc1,
                                                u16* __restrict__ WTg0, u16* __restrict__ WTc0,
                                                u16* __restrict__ WTg1, u16* __restrict__ WTc1){
  int z = blockIdx.y;
  const float* w = (z==0) ? wg0 : (z==1) ? wc0 : (z==2) ? wg1 : wc1;
  u16* WT       = (z==0) ? WTg0 : (z==1) ? WTc0 : (z==2) ? WTg1 : WTc1;
  int OUTr = (z==0 || z==2) ? 128 : 64;
  int F  = (z < 2) ? 65 : 128;
  int Fp = (z < 2) ? 72 : 128;
  int Kd = (z < 2) ? 384 : 640;
  int idx = blockIdx.x*256 + threadIdx.x;
  if (idx >= 128*Kd) return;
  int o = idx / Kd, k = idx - o*Kd;
  int m = k / Fp, f = k - m*Fp;
  float v = 0.f;
  if (o < OUTr && m < 5 && f < F) v = w[(long)(f*5 + m)*OUTr + o];
  WT[idx] = f2bf(v);
}

// hidden (f32) -> fp8 X0T rows (b, rowoff+u) + bf16 D cols (coloff+u); layer-0 extras: inp + pads
__global__ __launch_bounds__(256) void k_hx_build(const float* __restrict__ hx, const float* __restrict__ inp,
                                                  u8* __restrict__ X0T, u16* __restrict__ D,
                                                  int Fp, int rowoff, long ldD, int coloff, int l0extras){
  __shared__ float t[64*66];
  int b = blockIdx.x, n0 = blockIdx.y * 64;
  int tid = threadIdx.x;
  const float* hb = hx + (long)b*2048*64;
  long bn0 = (long)b*2048 + n0;
  for (int e = tid; e < 4096; e += 256){
    int u = e & 63, ni = e >> 6;            // lane->u: f32 read coalesced
    t[ni*66 + u] = hb[(long)(n0+ni)*64 + u];
  }
  __syncthreads();
  for (int e = tid; e < 4096; e += 256){
    int u = e >> 6, ni = e & 63;            // lane->ni: fp8 row write coalesced
    X0T[((long)b*Fp + rowoff + u)*2048 + n0 + ni] = f2e4(t[ni*66 + u]);
  }
  for (int e = tid; e < 4096; e += 256){
    int ni = e >> 6, u = e & 63;            // lane->u: D col write coalesced
    D[(bn0 + ni)*ldD + coloff + u] = f2bf(t[ni*66 + u]);
  }
  if (l0extras){
    if (tid < 64){
      float v = inp[(long)b*2048 + n0 + tid];
      X0T[((long)b*Fp)*2048 + n0 + tid] = f2e4(v);
      D[(bn0 + tid)*ldD] = f2bf(v);
    }
    for (int e = tid; e < 7*64; e += 256){
      int f = 65 + (e >> 6), ni = e & 63;
      X0T[((long)b*Fp + f)*2048 + n0 + ni] = 0;
    }
    for (int e = tid; e < 64*31; e += 256){
      int ni = e / 31, wc = e - ni*31;
      int col = (wc < 7) ? (65 + wc) : (353 + wc);   // {65..71, 360..383}
      D[(bn0 + ni)*ldD + col] = 0;
    }
  }
}

// ---------- bf16 GEMM core, BK=64 (dense) ----------
__device__ __forceinline__ void gemm_core(const u16* __restrict__ A, const u16* __restrict__ Bt,
                                          int K, long tM, long tC,
                                          u16* lA, u16* lB, f32x4 (&acc)[4][4]){
  int tid = threadIdx.x;
  int wv = tid >> 6, lane = tid & 63;
  int q = lane >> 4, r16 = lane & 15;

  const u16* ga[4]; const u16* gb[4];
  u16* la[4]; u16* lb[4];
  #pragma unroll
  for (int it = 0; it < 4; it++){
    int L = it*256 + tid;
    int r = L >> 3, g = (L & 7) ^ (r & 7);
    ga[it] = A  + (tM + r)*(long)K + g*8;
    gb[it] = Bt + (tC + r)*(long)K + g*8;
    la[it] = lA + (it*256 + wv*64)*8;
    lb[it] = lB + (it*256 + wv*64)*8;
  }

  #pragma unroll
  for (int i = 0; i < 4; i++)
    #pragma unroll
    for (int j = 0; j < 4; j++){ acc[i][j][0]=0.f; acc[i][j][1]=0.f; acc[i][j][2]=0.f; acc[i][j][3]=0.f; }

  int wm = wv & 1, wn = wv >> 1;
  int aoff[4][2], boff[4][2];
  #pragma unroll
  for (int s = 0; s < 4; s++){
    int m = wm*64 + s*16 + r16;
    int n = wn*64 + s*16 + r16;
    #pragma unroll
    for (int h = 0; h < 2; h++){
      aoff[s][h] = (m*8 + ((h*4 + q) ^ (m & 7))) * 8;
      boff[s][h] = (n*8 + ((h*4 + q) ^ (n & 7))) * 8;
    }
  }

  for (int k0 = 0; k0 < K; k0 += 64){
    __syncthreads();
    #pragma unroll
    for (int it = 0; it < 4; it++){
      gl_lds16(ga[it] + k0, la[it]);
      gl_lds16(gb[it] + k0, lb[it]);
    }
    asm volatile("s_waitcnt vmcnt(0)" ::: "memory");
    __syncthreads();
    #pragma unroll
    for (int h = 0; h < 2; h++){
      bf16x8 af[4], bfr[4];
      #pragma unroll
      for (int s = 0; s < 4; s++){
        af[s]  = *(const bf16x8*)&lA[aoff[s][h]];
        bfr[s] = *(const bf16x8*)&lB[boff[s][h]];
      }
      #pragma unroll
      for (int i = 0; i < 4; i++)
        #pragma unroll
        for (int j = 0; j < 4; j++)
          acc[i][j] = __builtin_amdgcn_mfma_f32_16x16x32_bf16(af[i], bfr[j], acc[i][j], 0, 0, 0);
    }
  }
}

// ---------- fp8 MX GEMM core, BK=128 bytes ----------
// Storage permutation sigma(g) = (g>>1)|((g&1)<<2): frag-read slot pattern
// (e*4+q)^(m&7), measured SQ_LDS_BANK_CONFLICT = 0. SCLB: B-operand MX scale.
// B-fragments are STREAMED one at a time (j-outer loop) to cut the register
// working set (~140 -> ~116 total incl. 64 acc AGPR) so __launch_bounds__(256,4)
// fits 4 blocks/CU (reg budget 128) -- R11 counters showed Occupancy 24%
// (2 blocks/CU, VGPR-capped), MfmaUtil 38%. Per-acc MFMA count/order per
// K-step unchanged -> numerically identical.
template<u32 SCLB>
__device__ __forceinline__ void gemm_core8(const u8* __restrict__ A, const u8* __restrict__ Bt,
                                           int K, long tM, long tC,
                                           u8* lA, u8* lB, f32x4 (&acc)[4][4]){
  int tid = threadIdx.x;
  int wv = tid >> 6, lane = tid & 63;
  int q = lane >> 4, r16 = lane & 15;

  const u8* ga[4]; const u8* gb[4];
  u8* la[4]; u8* lb[4];
  #pragma unroll
  for (int it = 0; it < 4; it++){
    int L = it*256 + tid;
    int r = L >> 3, x = (L & 7) ^ (r & 7);
    int g = ((x & 3) << 1) | (x >> 2);     // sigma^-1
    ga[it] = A  + (tM + r)*(long)K + g*16;
    gb[it] = Bt + (tC + r)*(long)K + g*16;
    la[it] = lA + (it*256 + wv*64)*16;
    lb[it] = lB + (it*256 + wv*64)*16;
  }

  #pragma unroll
  for (int i = 0; i < 4; i++)
    #pragma unroll
    for (int j = 0; j < 4; j++){ acc[i][j][0]=0.f; acc[i][j][1]=0.f; acc[i][j][2]=0.f; acc[i][j][3]=0.f; }

  int wm = wv & 1, wn = wv >> 1;
  int aoff[4][2], boff[4][2];
  #pragma unroll
  for (int s = 0; s < 4; s++){
    int m = wm*64 + s*16 + r16;
    int n = wn*64 + s*16 + r16;
    #pragma unroll
    for (int e = 0; e < 2; e++){
      aoff[s][e] = m*128 + ((e*4 + q) ^ (m & 7)) * 16;
      boff[s][e] = n*128 + ((e*4 + q) ^ (n & 7)) * 16;
    }
  }

  for (int k0 = 0; k0 < K; k0 += 128){
    __syncthreads();
    #pragma unroll
    for (int it = 0; it < 4; it++){
      gl_lds16(ga[it] + k0, la[it]);
      gl_lds16(gb[it] + k0, lb[it]);
    }
    asm volatile("s_waitcnt vmcnt(0)" ::: "memory");
    __syncthreads();
    i32x8 af[4];
    #pragma unroll
    for (int s = 0; s < 4; s++){
      uint4 a0 = *(const uint4*)&lA[aoff[s][0]];
      uint4 a1 = *(const uint4*)&lA[aoff[s][1]];
      i32x8 av; av[0]=a0.x; av[1]=a0.y; av[2]=a0.z; av[3]=a0.w; av[4]=a1.x; av[5]=a1.y; av[6]=a1.z; av[7]=a1.w;
      af[s] = av;
    }
    #pragma unroll
    for (int j = 0; j < 4; j++){
      uint4 b0 = *(const uint4*)&lB[boff[j][0]];
      uint4 b1 = *(const uint4*)&lB[boff[j][1]];
      i32x8 bv; bv[0]=b0.x; bv[1]=b0.y; bv[2]=b0.z; bv[3]=b0.w; bv[4]=b1.x; bv[5]=b1.y; bv[6]=b1.z; bv[7]=b1.w;
      #pragma unroll
      for (int i = 0; i < 4; i++)
        acc[i][j] = __builtin_amdgcn_mfma_scale_f32_16x16x128_f8f6f4(
                      af[i], bv, acc[i][j], 0, 0, 0, SCL_A, 0, SCLB);
    }
  }
}

// ---------- fp8 precompute: bz=0: R=S1@S0 -> Rq + RTq; bz=1: V=2*S0^2-I -> Vq ----------
// A=S0Tq ([gi][k]=S0[k][gi] x256), Bt=S1q/S0q (x256) -> acc[gi][gc] = (S1@S0)[gc][gi] / (S0^2)[gc][gi].
__global__ __launch_bounds__(256, 4) void gemm_pre8(const u8* __restrict__ S0Tq, const u8* __restrict__ S1q,
                                                    const u8* __restrict__ S0q,
                                                    u8* __restrict__ Rq, u8* __restrict__ RTq, u8* __restrict__ Vq){
  __shared__ u8 lA[16384];
  __shared__ u8 lB[16384];
  f32x4 acc[4][4];
  int bx, by, bz;
  xcd_swizzle(bx, by, bz);
  const u8* Bt = (bz == 0) ? S1q : S0q;
  long tM = (long)bx * 128, tC = (long)by * 128;
  gemm_core8<SCL_B256>(S0Tq, Bt, 2048, tM, tC, lA, lB, acc);

  int tid = threadIdx.x, wv = tid >> 6, lane = tid & 63;
  int q = lane >> 4, r16 = lane & 15, wm = wv & 1, wn = wv >> 1;
  #pragma unroll
  for (int i = 0; i < 4; i++){
    long gi = tM + wm*64 + i*16 + q*4;
    #pragma unroll
    for (int j = 0; j < 4; j++){
      long gc = tC + wn*64 + j*16 + r16;
      f32x4 v = acc[i][j];
      if (bz == 0){
        // v[r] = R[gc][gi+r]; Rq row-major R; RTq row-major R^T (A-operand for gemm_w8)
        *(u32*)(Rq + gc*2048 + gi) = pack4_e4(v[0]*256.f, v[1]*256.f, v[2]*256.f, v[3]*256.f);
        RTq[(gi+0)*2048 + gc] = f2e4(v[0]*256.f);
        RTq[(gi+1)*2048 + gc] = f2e4(v[1]*256.f);
        RTq[(gi+2)*2048 + gc] = f2e4(v[2]*256.f);
        RTq[(gi+3)*2048 + gc] = f2e4(v[3]*256.f);
      } else {
        float x0 = 2.f*v[0] - ((gi+0) == gc ? 1.f : 0.f);
        float x1 = 2.f*v[1] - ((gi+1) == gc ? 1.f : 0.f);
        float x2 = 2.f*v[2] - ((gi+2) == gc ? 1.f : 0.f);
        float x3 = 2.f*v[3] - ((gi+3) == gc ? 1.f : 0.f);
        *(u32*)(Vq + gc*2048 + gi) = pack4_e4(x0*256.f, x1*256.f, x2*256.f, x3*256.f);
      }
    }
  }
}

// ---------- fp8 precompute: W = 2*S1@R - S0 -> Wq ----------
// A=RTq ([gi][k]=R[k][gi] x256), Bt=S1q (x256) -> acc = (S1@R)[gc][gi]; S0 read bf16.
__global__ __launch_bounds__(256, 4) void gemm_w8(const u8* __restrict__ RTq, const u8* __restrict__ S1q,
                                                  const u16* __restrict__ S0, u8* __restrict__ Wq){
  __shared__ u8 lA[16384];
  __shared__ u8 lB[16384];
  f32x4 acc[4][4];
  int bx, by, bz;
  xcd_swizzle(bx, by, bz);
  long tM = (long)bx * 128, tC = (long)by * 128;
  gemm_core8<SCL_B256>(RTq, S1q, 2048, tM, tC, lA, lB, acc);

  int tid = threadIdx.x, wv = tid >> 6, lane = tid & 63;
  int q = lane >> 4, r16 = lane & 15, wm = wv & 1, wn = wv >> 1;
  #pragma unroll
  for (int i = 0; i < 4; i++){
    long gi = tM + wm*64 + i*16 + q*4;
    #pragma unroll
    for (int j = 0; j < 4; j++){
      long gc = tC + wn*64 + j*16 + r16;
      f32x4 v = acc[i][j];
      ushort4 x0 = *(const ushort4*)(S0 + gc*2048 + gi);
      *(u32*)(Wq + gc*2048 + gi) = pack4_e4((2.f*v[0] - bf2f(x0.x))*256.f,
                                            (2.f*v[1] - bf2f(x0.y))*256.f,
                                            (2.f*v[2] - bf2f(x0.z))*256.f,
                                            (2.f*v[3] - bf2f(x0.w))*256.f);
    }
  }
}

// ---------- fp8 batched diffusion (gate): z selects {S0,V,R,W}; writes D slice z+1 ----------
template<int FP>
__global__ __launch_bounds__(256, 4) void gemm_diff8(const u8* __restrict__ M0, const u8* __restrict__ M1,
                                                     const u8* __restrict__ M2, const u8* __restrict__ M3,
                                                     const u8* __restrict__ X, u16* __restrict__ D, long ldD){
  __shared__ u8 lA[16384];
  __shared__ u8 lB[16384];
  f32x4 acc[4][4];
  int bx, by, z;
  xcd_swizzle(bx, by, z);
  const u8* A = (z == 0) ? M0 : (z == 1) ? M1 : (z == 2) ? M2 : M3;
  long tM = (long)bx * 128, tC = (long)by * 128;
  gemm_core8<SCL_B1>(A, X, 2048, tM, tC, lA, lB, acc);

  int tid = threadIdx.x, wv = tid >> 6, lane = tid & 63;
  int q = lane >> 4, r16 = lane & 15, wm = wv & 1, wn = wv >> 1;
  int zb = (z + 1) * FP;
  #pragma unroll
  for (int i = 0; i < 4; i++){
    long gi = tM + wm*64 + i*16 + q*4;
    #pragma unroll
    for (int j = 0; j < 4; j++){
      int gc = (int)(tC + wn*64 + j*16 + r16);
      int b = gc / FP, f = gc - b*FP;
      long rb = (long)b*2048 + gi;
      f32x4 v = acc[i][j];
      D[(rb+0)*ldD + zb + f] = f2bf(v[0]);
      D[(rb+1)*ldD + zb + f] = f2bf(v[1]);
      D[(rb+2)*ldD + zb + f] = f2bf(v[2]);
      D[(rb+3)*ldD + zb + f] = f2bf(v[3]);
    }
  }
}

// ---------- fp8 candidate diffusion: Xr (2048 x 2048), writes D col (z+1)*Fp+fin+u ----------
__global__ __launch_bounds__(256, 4) void gemm_diff8_c(const u8* __restrict__ M0, const u8* __restrict__ M1,
                                                       const u8* __restrict__ M2, const u8* __restrict__ M3,
                                                       const u8* __restrict__ Xr, u16* __restrict__ D,
                                                       long ldD, int Fp, int fin){
  __shared__ u8 lA[16384];
  __shared__ u8 lB[16384];
  f32x4 acc[4][4];
  int bx, by, z;
  xcd_swizzle(bx, by, z);
  const u8* A = (z == 0) ? M0 : (z == 1) ? M1 : (z == 2) ? M2 : M3;
  long tM = (long)bx * 128, tC = (long)by * 128;
  gemm_core8<SCL_B1>(A, Xr, 2048, tM, tC, lA, lB, acc);

  int tid = threadIdx.x, wv = tid >> 6, lane = tid & 63;
  int q = lane >> 4, r16 = lane & 15, wm = wv & 1, wn = wv >> 1;
  int zb = (z + 1) * Fp + fin;
  #pragma unroll
  for (int i = 0; i < 4; i++){
    long gi = tM + wm*64 + i*16 + q*4;
    #pragma unroll
    for (int j = 0; j < 4; j++){
      int gc = (int)(tC + wn*64 + j*16 + r16);
      int b = gc >> 6, u = gc & 63;
      long rb = (long)b*2048 + gi;
      f32x4 v = acc[i][j];
      D[(rb+0)*ldD + zb + u] = f2bf(v[0]);
      D[(rb+1)*ldD + zb + u] = f2bf(v[1]);
      D[(rb+2)*ldD + zb + u] = f2bf(v[2]);
      D[(rb+3)*ldD + zb + u] = f2bf(v[3]);
    }
  }
}

// ---------- dense (bf16): OutT[c][i] = bf16( sum_k A[i,k]*Bt[c,k] ) ----------
__global__ __launch_bounds__(256) void gemm_dense(const u16* __restrict__ A, const u16* __restrict__ Bt,
                                                  u16* __restrict__ Out, int K, long ldOut){
  __shared__ u16 lA[8192];
  __shared__ u16 lB[8192];
  f32x4 acc[4][4];
  long tM = (long)blockIdx.x * 128, tC = (long)blockIdx.y * 128;
  gemm_core(A, Bt, K, tM, tC, lA, lB, acc);

  int tid = threadIdx.x, wv = tid >> 6, lane = tid & 63;
  int q = lane >> 4, r16 = lane & 15, wm = wv & 1, wn = wv >> 1;
  #pragma unroll
  for (int i = 0; i < 4; i++){
    long gi = tM + wm*64 + i*16 + q*4;
    #pragma unroll
    for (int j = 0; j < 4; j++){
      long gc = tC + wn*64 + j*16 + r16;
      f32x4 v = acc[i][j];
      ushort4 o;
      o.x = f2bf(v[0]); o.y = f2bf(v[1]); o.z = f2bf(v[2]); o.w = f2bf(v[3]);
      *(ushort4*)(Out + gc*ldOut + gi) = o;
    }
  }
}

// ---------- GRU epilogues ----------
__global__ __launch_bounds__(256) void k_gate_ep(const u16* __restrict__ GT, const float* __restrict__ bg,
                                                 const float* __restrict__ hid, u8* __restrict__ Xr8,
                                                 u16* __restrict__ D, long ldD, int coloff){
  __shared__ float t[64*66];
  __shared__ u16 tb[64*66];
  int b = blockIdx.x, n0 = blockIdx.y * 64;
  int tid = threadIdx.x;
  long bn0 = (long)b*2048 + n0;
  for (int e = tid; e < 4096; e += 256){
    int u = e & 63, ni = e >> 6;            // lane->u: f32 hid read coalesced
    t[ni*66 + u] = hid[(bn0 + ni)*64 + u];
  }
  __syncthreads();
  for (int e = tid; e < 4096; e += 256){
    int u = e >> 6, ni = e & 63;            // lane->ni: GT read + Xr8 write coalesced
    float r = sigf(bf2f(GT[(long)u*65536 + bn0 + ni]) + bg[u]);
    float pv = r * t[ni*66 + u];
    Xr8[((long)b*64 + u)*2048 + n0 + ni] = f2e4(pv);
    tb[ni*66 + u] = f2bf(pv);
  }
  __syncthreads();
  for (int e = tid; e < 4096; e += 256){
    int ni = e >> 6, u = e & 63;            // lane->u: D col write coalesced
    D[(bn0 + ni)*ldD + coloff + u] = tb[ni*66 + u];
  }
}

__global__ __launch_bounds__(256) void k_cand_ep(const u16* __restrict__ CT, const u16* __restrict__ GT,
                                                 const float* __restrict__ bc, const float* __restrict__ bg,
                                                 const float* __restrict__ hx, float* __restrict__ hout,
                                                 u8* __restrict__ X0T_next, u16* __restrict__ Dnext,
                                                 const float* __restrict__ wproj, const float* __restrict__ bproj,
                                                 float* __restrict__ out){
  __shared__ u16 tc[64*66];
  __shared__ u16 tu[64*66];
  __shared__ u16 th[64*66];
  int b = blockIdx.x, n0 = blockIdx.y * 64;
  int tid = threadIdx.x;
  long bn0 = (long)b*2048 + n0;
  for (int e = tid; e < 4096; e += 256){
    int u = e >> 6, ni = e & 63;
    float cv = tanhf(bf2f(CT[(long)u*65536 + bn0 + ni]) + bc[u]);
    float uv = sigf(bf2f(GT[(long)(64+u)*65536 + bn0 + ni]) + bg[64+u]);
    tc[ni*66 + u] = f2bf(cv);
    tu[ni*66 + u] = f2bf(uv);
  }
  __syncthreads();
  int lane = tid & 63, wv = tid >> 6;
  for (int it = 0; it < 16; ++it){
    int ni = it*4 + wv, u = lane;
    float hxv = hx[(bn0 + ni)*64 + u];
    float uv = bf2f(tu[ni*66 + u]), cv = bf2f(tc[ni*66 + u]);
    float h = uv*hxv + (1.f - uv)*cv;
    hout[(bn0 + ni)*64 + u] = h;
    if (Dnext) Dnext[(bn0 + ni)*640 + u] = f2bf(h);
    th[ni*66 + u] = f2bf(h);
    if (wproj){
      float v = h * wproj[u];
      for (int off = 32; off; off >>= 1) v += __shfl_down(v, off, 64);
      if (lane == 0) out[(long)b*2048 + n0 + ni] = v + bproj[0];
    }
  }
  __syncthreads();
  if (X0T_next){
    for (int e = tid; e < 4096; e += 256){
      int u = e >> 6, ni = e & 63;          // lane->ni: fp8 row write coalesced
      X0T_next[((long)b*128 + u)*2048 + n0 + ni] = f2e4(bf2f(th[ni*66 + u]));
    }
  }
}

// ---------- launch ----------
extern "C" void kernel_launch(void* const* d_in, const int* in_sizes, int n_in,
                              void* d_out, int out_size, void* d_ws, size_t ws_size,
                              hipStream_t stream){
  (void)in_sizes; (void)n_in; (void)out_size; (void)ws_size;
  const float* inputs = (const float*)d_in[0];
  const float* hidden = (const float*)d_in[1];
  const float* adj    = (const float*)d_in[2];
  const float* wg0 = (const float*)d_in[3];
  const float* bg0 = (const float*)d_in[4];
  const float* wc0 = (const float*)d_in[5];
  const float* bc0 = (const float*)d_in[6];
  const float* wg1 = (const float*)d_in[7];
  const float* bg1 = (const float*)d_in[8];
  const float* wc1 = (const float*)d_in[9];
  const float* bc1 = (const float*)d_in[10];
  const float* wp  = (const float*)d_in[11];
  const float* bp  = (const float*)d_in[12];
  float* out = (float*)d_out;

  char* p = (char*)d_ws;
  auto alloc = [&](size_t bytes)->char*{ char* r = p; p += (bytes + 255) & ~(size_t)255; return r; };
  float* inv_rs = (float*)alloc(2048*4);
  float* cs     = (float*)alloc(2048*4);
  const size_t SB  = (size_t)2048*2048*2;   // bf16 NxN
  const size_t SB8 = (size_t)2048*2048;     // fp8 NxN
  u16* S0  = (u16*)alloc(SB);
  u8*  S0q = (u8*)alloc(SB8);
  u8*  S0Tq= (u8*)alloc(SB8);
  u8*  S1q = (u8*)alloc(SB8);
  u8*  Rq  = (u8*)alloc(SB8);
  u8*  RTq = (u8*)alloc(SB8);
  u8*  Vq  = (u8*)alloc(SB8);
  u8*  Wq  = (u8*)alloc(SB8);
  u8*  X0a8 = (u8*)alloc((size_t)2304*2048); // layer0 cat, fp8, Fp=72
  u8*  X0b8 = (u8*)alloc((size_t)4096*2048); // layer1 cat, fp8, Fp=128
  u8*  Xr8  = (u8*)alloc(SB8);               // r*hx, fp8
  u16* D   = (u16*)alloc((size_t)65536*640*2);
  u16* GT = (u16*)alloc((size_t)128*65536*2);
  u16* CT = (u16*)alloc((size_t)128*65536*2);
  u16* WTg0 = (u16*)alloc((size_t)128*384*2);
  u16* WTc0 = (u16*)alloc((size_t)128*384*2);
  u16* WTg1 = (u16*)alloc((size_t)128*640*2);
  u16* WTc1 = (u16*)alloc((size_t)128*640*2);

  const float* hid0 = hidden;
  const float* hid1 = hidden + (size_t)4194304;
  float* h0out = out + 65536;
  float* h1out = out + 65536 + 4194304;

  // ---- setup ----
  k_rowsum<<<2048, 256, 0, stream>>>(adj, inv_rs, cs);
  k_colsum2<<<dim3(32,16), 256, 0, stream>>>(adj, cs);
  k_build_S<<<dim3(32,32), 256, 0, stream>>>(adj, inv_rs, cs, S0, S0q, S0Tq, S1q);
  k_packW4<<<dim3(320,4), 256, 0, stream>>>(wg0, wc0, wg1, wc1, WTg0, WTc0, WTg1, WTc1);
  k_hx_build<<<dim3(32,32), 256, 0, stream>>>(hid0, inputs, X0a8, D, 72, 1, 384, 1, 1);

  // ---- precompute diffusion operators R, V, W (fp8 MX compute) ----
  gemm_pre8<<<dim3(16,16,2), 256, 0, stream>>>(S0Tq, S1q, S0q, Rq, RTq, Vq);
  gemm_w8  <<<dim3(16,16),   256, 0, stream>>>(RTq, S1q, S0, Wq);

  dim3 gD0(16, 18, 4), gD1(16, 32, 4), gDc(16, 16, 4), gDen(512, 1), gE(32, 32);

  // ---- layer 0 gate ----
  gemm_diff8<72><<<gD0, 256, 0, stream>>>(S0q, Vq, Rq, Wq, X0a8, D, 384);
  gemm_dense<<<gDen, 256, 0, stream>>>(D, WTg0, GT, 384, 65536);
  k_gate_ep<<<gE, 256, 0, stream>>>(GT, bg0, hid0, Xr8, D, 384, 1);

  // ---- layer 0 candidate (diffuse only r*hx; inp cols reused from gate pass) ----
  gemm_diff8_c<<<gDc, 256, 0, stream>>>(S0q, Vq, Rq, Wq, Xr8, D, 384, 72, 1);
  gemm_dense<<<gDen, 256, 0, stream>>>(D, WTc0, CT, 384, 65536);
  k_cand_ep<<<gE, 256, 0, stream>>>(CT, GT, bc0, bg0, hid0, h0out, X0b8, D, nullptr, nullptr, nullptr);

  // ---- layer 1 build ----
  k_hx_build<<<dim3(32,32), 256, 0, stream>>>(hid1, nullptr, X0b8, D, 128, 64, 640, 64, 0);

  // ---- layer 1 gate ----
  gemm_diff8<128><<<gD1, 256, 0, stream>>>(S0q, Vq, Rq, Wq, X0b8, D, 640);
  gemm_dense<<<gDen, 256, 0, stream>>>(D, WTg1, GT, 640, 65536);
  k_gate_ep<<<gE, 256, 0, stream>>>(GT, bg1, hid1, Xr8, D, 640, 64);

  // ---- layer 1 candidate ----
  gemm_diff8_c<<<gDc, 256, 0, stream>>>(S0q, Vq, Rq, Wq, Xr8, D, 640, 128, 64);
  gemm_dense<<<gDen, 256, 0, stream>>>(D, WTc1, CT, 640, 65536);
  k_cand_ep<<<gE, 256, 0, stream>>>(CT, GT, bc1, bg1, hid1, h1out, nullptr, nullptr, wp, bp, out);
}

// Round 14
// 515.367 us; speedup vs baseline: 1.2328x; 1.0311x over previous
//
#include <hip/hip_runtime.h>

typedef unsigned short u16;
typedef unsigned char u8;
typedef unsigned int u32;
typedef float f32x4 __attribute__((ext_vector_type(4)));
typedef __bf16 bf16x8 __attribute__((ext_vector_type(8)));
typedef int i32x8 __attribute__((ext_vector_type(8)));

// MX scale bytes (E8M0: 2^(b-127)): 0x77 = 2^-8 (operands quantized x256),
// 0x7F = 1.0 (X inputs).
#define SCL_A 0x77777777u
#define SCL_B1 0x7F7F7F7Fu
#define SCL_B256 0x77777777u

// ---------- helpers ----------
__device__ __forceinline__ u16 f2bf(float f){
  u32 u = __builtin_bit_cast(u32, f);
  u32 r = (u + 0x7fffu + ((u >> 16) & 1u)) >> 16;
  return (u16)r;
}
__device__ __forceinline__ float bf2f(u16 h){
  return __builtin_bit_cast(float, ((u32)h) << 16);
}
__device__ __forceinline__ u8 f2e4(float x){
  return (u8)(__builtin_amdgcn_cvt_pk_fp8_f32(x, x, 0, false) & 0xff);
}
__device__ __forceinline__ u32 pack4_e4(float a, float b, float c, float d){
  int w = __builtin_amdgcn_cvt_pk_fp8_f32(a, b, 0, false);
  w = __builtin_amdgcn_cvt_pk_fp8_f32(c, d, w, true);
  return (u32)w;
}
__device__ __forceinline__ void gl_lds16(const void* g, void* l){
  __builtin_amdgcn_global_load_lds((__attribute__((address_space(1))) void*)g,
                                   (__attribute__((address_space(3))) void*)l,
                                   16, 0, 0);
}
__device__ __forceinline__ float sigf(float x){ return 1.f/(1.f + __expf(-x)); }

// XCD-chunked block swizzle (T1). Requires nwg % 8 == 0 (all swizzled grids:
// 1152/1024/2048/512/256). Remap hw id -> contiguous logical chunk per XCD.
__device__ __forceinline__ void xcd_swizzle(int& x, int& y, int& z){
  int gx = gridDim.x, gy = gridDim.y;
  int nwg = gx * gy * gridDim.z;
  int lid = blockIdx.x + gx*(blockIdx.y + gy*blockIdx.z);
  int cpx = nwg >> 3;
  int swz = (lid & 7)*cpx + (lid >> 3);
  x = swz % gx;
  int rest = swz / gx;
  y = rest % gy;
  z = rest / gy;
}

// ---------- sums ----------
__global__ __launch_bounds__(256) void k_rowsum(const float* __restrict__ adj, float* __restrict__ inv_rs,
                                                float* __restrict__ cs){
  int j = blockIdx.x; int tid = threadIdx.x;
  float s = 0.f;
  for (int i = tid; i < 2048; i += 256) s += adj[(long)j*2048 + i];
  for (int off = 32; off; off >>= 1) s += __shfl_down(s, off, 64);
  __shared__ float red[4];
  if ((tid & 63) == 0) red[tid >> 6] = s;
  __syncthreads();
  if (tid == 0){
    float t = red[0] + red[1] + red[2] + red[3];
    inv_rs[j] = 1.f / fmaxf(t, 1e-8f);
    cs[j] = 0.f;   // zero for k_colsum2's atomics (stream-ordered after this kernel)
  }
}

__global__ __launch_bounds__(256) void k_colsum2(const float* __restrict__ adj, float* __restrict__ cs){
  int j0 = blockIdx.x * 64, i0 = blockIdx.y * 128;
  int jj = threadIdx.x & 63, w = threadIdx.x >> 6;
  float s = 0.f;
  for (int i = w; i < 128; i += 4) s += adj[(long)(i0+i)*2048 + j0 + jj];
  __shared__ float red[256];
  red[threadIdx.x] = s;
  __syncthreads();
  if (w == 0){
    float t = red[jj] + red[64+jj] + red[128+jj] + red[192+jj];
    atomicAdd(&cs[j0+jj], t);
  }
}

// Merged S-build: one adj tile read ->
//   S0Tq[j][i] = e4m3(adj[j][i]*inv_rs[j] x256)   (= S0^T row-major, fp8)
//   S1q [j][i] = e4m3(adj[j][i]/max(cs[i]) x256)  (= S1 row-major, fp8)
//   S0  [i][j] = bf16(adj[j][i]*inv_rs[j]), S0q = e4m3(S0 x256)  (LDS transpose)
__global__ __launch_bounds__(256) void k_build_S(const float* __restrict__ adj,
                                                 const float* __restrict__ inv_rs,
                                                 const float* __restrict__ cs,
                                                 u16* __restrict__ S0, u8* __restrict__ S0q,
                                                 u8* __restrict__ S0Tq, u8* __restrict__ S1q){
  __shared__ float t[64*66];
  __shared__ float rsl[64];
  __shared__ float icl[64];
  int i0 = blockIdx.x * 64, j0 = blockIdx.y * 64;
  int tid = threadIdx.x;
  if (tid < 64) rsl[tid] = inv_rs[j0 + tid];
  else if (tid >= 64 && tid < 128) icl[tid-64] = 1.f / fmaxf(cs[i0 + tid-64], 1e-8f);
  __syncthreads();
  for (int e = tid; e < 4096; e += 256){
    int jj = e >> 6, ii = e & 63;                 // lane varies ii: adj read + fp8 writes coalesced
    float a = adj[(long)(j0+jj)*2048 + i0 + ii];
    t[jj*66 + ii] = a;
    long o = (long)(j0+jj)*2048 + i0 + ii;
    S0Tq[o] = f2e4(a * rsl[jj] * 256.f);
    S1q[o]  = f2e4(a * icl[ii] * 256.f);
  }
  __syncthreads();
  for (int e = tid; e < 4096; e += 256){
    int ii = e >> 6, jj = e & 63;                 // lane varies jj: S0/S0q writes coalesced
    u16 vb = f2bf(t[jj*66 + ii] * rsl[jj]);       // LDS stride 66: 2-way bank alias (free, m136)
    long o = (long)(i0+ii)*2048 + j0 + jj;
    S0[o] = vb;
    S0q[o] = f2e4(bf2f(vb)*256.f);
  }
}

// Merged weight pack: z selects {wg0,wc0,wg1,wc1}. WT[o][k]=w[(f*5+m)*OUTr+o],
// k=(m,f) with per-z (OUTr,F,Fp,Kd); zero-padded.
__global__ __launch_bounds__(256) void k_packW4(const float* __restrict__ wg0, const float* __restrict__ wc0,
                                                const float* __restrict__ wg1, const float* __restrict__ wc1,
                                                u16* __restrict__ WTg0, u16* __restrict__ WTc0,
                                                u16* __restrict__ WTg1, u16* __restrict__ WTc1){
  int z = blockIdx.y;
  const float* w = (z==0) ? wg0 : (z==1) ? wc0 : (z==2) ? wg1 : wc1;
  u16* WT       = (z==0) ? WTg0 : (z==1) ? WTc0 : (z==2) ? WTg1 : WTc1;
  int OUTr = (z==0 || z==2) ? 128 : 64;
  int F  = (z < 2) ? 65 : 128;
  int Fp = (z < 2) ? 72 : 128;
  int Kd = (z < 2) ? 384 : 640;
  int idx = blockIdx.x*256 + threadIdx.x;
  if (idx >= 128*Kd) return;
  int o = idx / Kd, k = idx - o*Kd;
  int m = k / Fp, f = k - m*Fp;
  float v = 0.f;
  if (o < OUTr && m < 5 && f < F) v = w[(long)(f*5 + m)*OUTr + o];
  WT[idx] = f2bf(v);
}

// hidden (f32) -> fp8 X0T rows (b, rowoff+u) + bf16 D cols (coloff+u); layer-0 extras: inp + pads
__global__ __launch_bounds__(256) void k_hx_build(const float* __restrict__ hx, const float* __restrict__ inp,
                                                  u8* __restrict__ X0T, u16* __restrict__ D,
                                                  int Fp, int rowoff, long ldD, int coloff, int l0extras){
  __shared__ float t[64*66];
  int b = blockIdx.x, n0 = blockIdx.y * 64;
  int tid = threadIdx.x;
  const float* hb = hx + (long)b*2048*64;
  long bn0 = (long)b*2048 + n0;
  for (int e = tid; e < 4096; e += 256){
    int u = e & 63, ni = e >> 6;            // lane->u: f32 read coalesced
    t[ni*66 + u] = hb[(long)(n0+ni)*64 + u];
  }
  __syncthreads();
  for (int e = tid; e < 4096; e += 256){
    int u = e >> 6, ni = e & 63;            // lane->ni: fp8 row write coalesced
    X0T[((long)b*Fp + rowoff + u)*2048 + n0 + ni] = f2e4(t[ni*66 + u]);
  }
  for (int e = tid; e < 4096; e += 256){
    int ni = e >> 6, u = e & 63;            // lane->u: D col write coalesced
    D[(bn0 + ni)*ldD + coloff + u] = f2bf(t[ni*66 + u]);
  }
  if (l0extras){
    if (tid < 64){
      float v = inp[(long)b*2048 + n0 + tid];
      X0T[((long)b*Fp)*2048 + n0 + tid] = f2e4(v);
      D[(bn0 + tid)*ldD] = f2bf(v);
    }
    for (int e = tid; e < 7*64; e += 256){
      int f = 65 + (e >> 6), ni = e & 63;
      X0T[((long)b*Fp + f)*2048 + n0 + ni] = 0;
    }
    for (int e = tid; e < 64*31; e += 256){
      int ni = e / 31, wc = e - ni*31;
      int col = (wc < 7) ? (65 + wc) : (353 + wc);   // {65..71, 360..383}
      D[(bn0 + ni)*ldD + col] = 0;
    }
  }
}

// ---------- bf16 GEMM core, BK=64 (dense) ----------
__device__ __forceinline__ void gemm_core(const u16* __restrict__ A, const u16* __restrict__ Bt,
                                          int K, long tM, long tC,
                                          u16* lA, u16* lB, f32x4 (&acc)[4][4]){
  int tid = threadIdx.x;
  int wv = tid >> 6, lane = tid & 63;
  int q = lane >> 4, r16 = lane & 15;

  const u16* ga[4]; const u16* gb[4];
  u16* la[4]; u16* lb[4];
  #pragma unroll
  for (int it = 0; it < 4; it++){
    int L = it*256 + tid;
    int r = L >> 3, g = (L & 7) ^ (r & 7);
    ga[it] = A  + (tM + r)*(long)K + g*8;
    gb[it] = Bt + (tC + r)*(long)K + g*8;
    la[it] = lA + (it*256 + wv*64)*8;
    lb[it] = lB + (it*256 + wv*64)*8;
  }

  #pragma unroll
  for (int i = 0; i < 4; i++)
    #pragma unroll
    for (int j = 0; j < 4; j++){ acc[i][j][0]=0.f; acc[i][j][1]=0.f; acc[i][j][2]=0.f; acc[i][j][3]=0.f; }

  int wm = wv & 1, wn = wv >> 1;
  int aoff[4][2], boff[4][2];
  #pragma unroll
  for (int s = 0; s < 4; s++){
    int m = wm*64 + s*16 + r16;
    int n = wn*64 + s*16 + r16;
    #pragma unroll
    for (int h = 0; h < 2; h++){
      aoff[s][h] = (m*8 + ((h*4 + q) ^ (m & 7))) * 8;
      boff[s][h] = (n*8 + ((h*4 + q) ^ (n & 7))) * 8;
    }
  }

  for (int k0 = 0; k0 < K; k0 += 64){
    __syncthreads();
    #pragma unroll
    for (int it = 0; it < 4; it++){
      gl_lds16(ga[it] + k0, la[it]);
      gl_lds16(gb[it] + k0, lb[it]);
    }
    asm volatile("s_waitcnt vmcnt(0)" ::: "memory");
    __syncthreads();
    #pragma unroll
    for (int h = 0; h < 2; h++){
      bf16x8 af[4], bfr[4];
      #pragma unroll
      for (int s = 0; s < 4; s++){
        af[s]  = *(const bf16x8*)&lA[aoff[s][h]];
        bfr[s] = *(const bf16x8*)&lB[boff[s][h]];
      }
      #pragma unroll
      for (int i = 0; i < 4; i++)
        #pragma unroll
        for (int j = 0; j < 4; j++)
          acc[i][j] = __builtin_amdgcn_mfma_f32_16x16x32_bf16(af[i], bfr[j], acc[i][j], 0, 0, 0);
    }
  }
}

// ---------- fp8 MX GEMM core, BK=128 bytes ----------
// Storage permutation sigma(g) = (g>>1)|((g&1)<<2): frag-read slot pattern
// (e*4+q)^(m&7), measured SQ_LDS_BANK_CONFLICT = 0. SCLB: B-operand MX scale.
// B-fragments streamed (j-outer) -> ~128 total regs -> 4 blocks/CU budget.
template<u32 SCLB>
__device__ __forceinline__ void gemm_core8(const u8* __restrict__ A, const u8* __restrict__ Bt,
                                           int K, long tM, long tC,
                                           u8* lA, u8* lB, f32x4 (&acc)[4][4]){
  int tid = threadIdx.x;
  int wv = tid >> 6, lane = tid & 63;
  int q = lane >> 4, r16 = lane & 15;

  const u8* ga[4]; const u8* gb[4];
  u8* la[4]; u8* lb[4];
  #pragma unroll
  for (int it = 0; it < 4; it++){
    int L = it*256 + tid;
    int r = L >> 3, x = (L & 7) ^ (r & 7);
    int g = ((x & 3) << 1) | (x >> 2);     // sigma^-1
    ga[it] = A  + (tM + r)*(long)K + g*16;
    gb[it] = Bt + (tC + r)*(long)K + g*16;
    la[it] = lA + (it*256 + wv*64)*16;
    lb[it] = lB + (it*256 + wv*64)*16;
  }

  #pragma unroll
  for (int i = 0; i < 4; i++)
    #pragma unroll
    for (int j = 0; j < 4; j++){ acc[i][j][0]=0.f; acc[i][j][1]=0.f; acc[i][j][2]=0.f; acc[i][j][3]=0.f; }

  int wm = wv & 1, wn = wv >> 1;
  int aoff[4][2], boff[4][2];
  #pragma unroll
  for (int s = 0; s < 4; s++){
    int m = wm*64 + s*16 + r16;
    int n = wn*64 + s*16 + r16;
    #pragma unroll
    for (int e = 0; e < 2; e++){
      aoff[s][e] = m*128 + ((e*4 + q) ^ (m & 7)) * 16;
      boff[s][e] = n*128 + ((e*4 + q) ^ (n & 7)) * 16;
    }
  }

  for (int k0 = 0; k0 < K; k0 += 128){
    __syncthreads();
    #pragma unroll
    for (int it = 0; it < 4; it++){
      gl_lds16(ga[it] + k0, la[it]);
      gl_lds16(gb[it] + k0, lb[it]);
    }
    asm volatile("s_waitcnt vmcnt(0)" ::: "memory");
    __syncthreads();
    i32x8 af[4];
    #pragma unroll
    for (int s = 0; s < 4; s++){
      uint4 a0 = *(const uint4*)&lA[aoff[s][0]];
      uint4 a1 = *(const uint4*)&lA[aoff[s][1]];
      i32x8 av; av[0]=a0.x; av[1]=a0.y; av[2]=a0.z; av[3]=a0.w; av[4]=a1.x; av[5]=a1.y; av[6]=a1.z; av[7]=a1.w;
      af[s] = av;
    }
    #pragma unroll
    for (int j = 0; j < 4; j++){
      uint4 b0 = *(const uint4*)&lB[boff[j][0]];
      uint4 b1 = *(const uint4*)&lB[boff[j][1]];
      i32x8 bv; bv[0]=b0.x; bv[1]=b0.y; bv[2]=b0.z; bv[3]=b0.w; bv[4]=b1.x; bv[5]=b1.y; bv[6]=b1.z; bv[7]=b1.w;
      #pragma unroll
      for (int i = 0; i < 4; i++)
        acc[i][j] = __builtin_amdgcn_mfma_scale_f32_16x16x128_f8f6f4(
                      af[i], bv, acc[i][j], 0, 0, 0, SCL_A, 0, SCLB);
    }
  }
}

// ---------- fp8 precompute: bz=0: R=S1@S0 -> Rq + RTq; bz=1: V=2*S0^2-I -> Vq ----------
__global__ __launch_bounds__(256, 4) void gemm_pre8(const u8* __restrict__ S0Tq, const u8* __restrict__ S1q,
                                                    const u8* __restrict__ S0q,
                                                    u8* __restrict__ Rq, u8* __restrict__ RTq, u8* __restrict__ Vq){
  __shared__ u8 lA[16384];
  __shared__ u8 lB[16384];
  f32x4 acc[4][4];
  int bx, by, bz;
  xcd_swizzle(bx, by, bz);
  const u8* Bt = (bz == 0) ? S1q : S0q;
  long tM = (long)bx * 128, tC = (long)by * 128;
  gemm_core8<SCL_B256>(S0Tq, Bt, 2048, tM, tC, lA, lB, acc);

  int tid = threadIdx.x, wv = tid >> 6, lane = tid & 63;
  int q = lane >> 4, r16 = lane & 15, wm = wv & 1, wn = wv >> 1;
  #pragma unroll
  for (int i = 0; i < 4; i++){
    long gi = tM + wm*64 + i*16 + q*4;
    #pragma unroll
    for (int j = 0; j < 4; j++){
      long gc = tC + wn*64 + j*16 + r16;
      f32x4 v = acc[i][j];
      if (bz == 0){
        *(u32*)(Rq + gc*2048 + gi) = pack4_e4(v[0]*256.f, v[1]*256.f, v[2]*256.f, v[3]*256.f);
        RTq[(gi+0)*2048 + gc] = f2e4(v[0]*256.f);
        RTq[(gi+1)*2048 + gc] = f2e4(v[1]*256.f);
        RTq[(gi+2)*2048 + gc] = f2e4(v[2]*256.f);
        RTq[(gi+3)*2048 + gc] = f2e4(v[3]*256.f);
      } else {
        float x0 = 2.f*v[0] - ((gi+0) == gc ? 1.f : 0.f);
        float x1 = 2.f*v[1] - ((gi+1) == gc ? 1.f : 0.f);
        float x2 = 2.f*v[2] - ((gi+2) == gc ? 1.f : 0.f);
        float x3 = 2.f*v[3] - ((gi+3) == gc ? 1.f : 0.f);
        *(u32*)(Vq + gc*2048 + gi) = pack4_e4(x0*256.f, x1*256.f, x2*256.f, x3*256.f);
      }
    }
  }
}

// ---------- fp8 precompute: W = 2*S1@R - S0 -> Wq ----------
__global__ __launch_bounds__(256, 4) void gemm_w8(const u8* __restrict__ RTq, const u8* __restrict__ S1q,
                                                  const u16* __restrict__ S0, u8* __restrict__ Wq){
  __shared__ u8 lA[16384];
  __shared__ u8 lB[16384];
  f32x4 acc[4][4];
  int bx, by, bz;
  xcd_swizzle(bx, by, bz);
  long tM = (long)bx * 128, tC = (long)by * 128;
  gemm_core8<SCL_B256>(RTq, S1q, 2048, tM, tC, lA, lB, acc);

  int tid = threadIdx.x, wv = tid >> 6, lane = tid & 63;
  int q = lane >> 4, r16 = lane & 15, wm = wv & 1, wn = wv >> 1;
  #pragma unroll
  for (int i = 0; i < 4; i++){
    long gi = tM + wm*64 + i*16 + q*4;
    #pragma unroll
    for (int j = 0; j < 4; j++){
      long gc = tC + wn*64 + j*16 + r16;
      f32x4 v = acc[i][j];
      ushort4 x0 = *(const ushort4*)(S0 + gc*2048 + gi);
      *(u32*)(Wq + gc*2048 + gi) = pack4_e4((2.f*v[0] - bf2f(x0.x))*256.f,
                                            (2.f*v[1] - bf2f(x0.y))*256.f,
                                            (2.f*v[2] - bf2f(x0.z))*256.f,
                                            (2.f*v[3] - bf2f(x0.w))*256.f);
    }
  }
}

// ---------- fp8 batched diffusion (gate): z selects {S0,V,R,W}; writes D slice z+1 ----------
template<int FP>
__global__ __launch_bounds__(256, 4) void gemm_diff8(const u8* __restrict__ M0, const u8* __restrict__ M1,
                                                     const u8* __restrict__ M2, const u8* __restrict__ M3,
                                                     const u8* __restrict__ X, u16* __restrict__ D, long ldD){
  __shared__ u8 lA[16384];
  __shared__ u8 lB[16384];
  f32x4 acc[4][4];
  int bx, by, z;
  xcd_swizzle(bx, by, z);
  const u8* A = (z == 0) ? M0 : (z == 1) ? M1 : (z == 2) ? M2 : M3;
  long tM = (long)bx * 128, tC = (long)by * 128;
  gemm_core8<SCL_B1>(A, X, 2048, tM, tC, lA, lB, acc);

  int tid = threadIdx.x, wv = tid >> 6, lane = tid & 63;
  int q = lane >> 4, r16 = lane & 15, wm = wv & 1, wn = wv >> 1;
  int zb = (z + 1) * FP;
  #pragma unroll
  for (int i = 0; i < 4; i++){
    long gi = tM + wm*64 + i*16 + q*4;
    #pragma unroll
    for (int j = 0; j < 4; j++){
      int gc = (int)(tC + wn*64 + j*16 + r16);
      int b = gc / FP, f = gc - b*FP;
      long rb = (long)b*2048 + gi;
      f32x4 v = acc[i][j];
      D[(rb+0)*ldD + zb + f] = f2bf(v[0]);
      D[(rb+1)*ldD + zb + f] = f2bf(v[1]);
      D[(rb+2)*ldD + zb + f] = f2bf(v[2]);
      D[(rb+3)*ldD + zb + f] = f2bf(v[3]);
    }
  }
}

// ---------- fp8 candidate diffusion: Xr (2048 x 2048), writes D col (z+1)*Fp+fin+u ----------
__global__ __launch_bounds__(256, 4) void gemm_diff8_c(const u8* __restrict__ M0, const u8* __restrict__ M1,
                                                       const u8* __restrict__ M2, const u8* __restrict__ M3,
                                                       const u8* __restrict__ Xr, u16* __restrict__ D,
                                                       long ldD, int Fp, int fin){
  __shared__ u8 lA[16384];
  __shared__ u8 lB[16384];
  f32x4 acc[4][4];
  int bx, by, z;
  xcd_swizzle(bx, by, z);
  const u8* A = (z == 0) ? M0 : (z == 1) ? M1 : (z == 2) ? M2 : M3;
  long tM = (long)bx * 128, tC = (long)by * 128;
  gemm_core8<SCL_B1>(A, Xr, 2048, tM, tC, lA, lB, acc);

  int tid = threadIdx.x, wv = tid >> 6, lane = tid & 63;
  int q = lane >> 4, r16 = lane & 15, wm = wv & 1, wn = wv >> 1;
  int zb = (z + 1) * Fp + fin;
  #pragma unroll
  for (int i = 0; i < 4; i++){
    long gi = tM + wm*64 + i*16 + q*4;
    #pragma unroll
    for (int j = 0; j < 4; j++){
      int gc = (int)(tC + wn*64 + j*16 + r16);
      int b = gc >> 6, u = gc & 63;
      long rb = (long)b*2048 + gi;
      f32x4 v = acc[i][j];
      D[(rb+0)*ldD + zb + u] = f2bf(v[0]);
      D[(rb+1)*ldD + zb + u] = f2bf(v[1]);
      D[(rb+2)*ldD + zb + u] = f2bf(v[2]);
      D[(rb+3)*ldD + zb + u] = f2bf(v[3]);
    }
  }
}

// ---------- fused dense + gate epilogue ----------
// Block bx: tokens [tM, tM+128), all 128 channels (tC=0).
// wn==0 waves (c<64): r = sig(acc+bg[c]); pv = r*hx -> Xr8 (e4m3, u-major) + D col coloff+c (bf16).
// wn==1 waves (c in [64,128)): GT[c][token] = bf16(sig(acc+bg[c]))  (pre-sigmoided update gate).
__global__ __launch_bounds__(256) void gemm_dense_gate(const u16* __restrict__ A, const u16* __restrict__ Bt,
                                                       int K, const float* __restrict__ bg,
                                                       const float* __restrict__ hx,
                                                       u16* __restrict__ GT,
                                                       u8* __restrict__ Xr8,
                                                       u16* __restrict__ D, long ldD, int coloff){
  __shared__ __align__(16) u8 smem[32768];
  u16* lA = (u16*)smem;
  u16* lB = (u16*)(smem + 16384);
  f32x4 acc[4][4];
  long tM = (long)blockIdx.x * 128;
  gemm_core(A, Bt, K, tM, 0, lA, lB, acc);

  int tid = threadIdx.x, wv = tid >> 6, lane = tid & 63;
  int q = lane >> 4, r16 = lane & 15, wm = wv & 1, wn = wv >> 1;
  int b = (int)(tM >> 11), n0 = (int)(tM & 2047);
  u16* stg16 = (u16*)smem;          // [128][66] pv bf16 (reuses core LDS)
  u8*  stg8  = smem + 16896;        // [64][132] pv e4m3

  __syncthreads();                  // all waves done reading core LDS
  if (wn == 0){
    #pragma unroll
    for (int i = 0; i < 4; i++){
      int tokb = wm*64 + i*16 + q*4;
      long gtok = tM + tokb;
      #pragma unroll
      for (int j = 0; j < 4; j++){
        int c = j*16 + r16;
        float bgc = bg[c];
        f32x4 v = acc[i][j];
        float p0 = sigf(v[0] + bgc) * hx[(gtok+0)*64 + c];
        float p1 = sigf(v[1] + bgc) * hx[(gtok+1)*64 + c];
        float p2 = sigf(v[2] + bgc) * hx[(gtok+2)*64 + c];
        float p3 = sigf(v[3] + bgc) * hx[(gtok+3)*64 + c];
        stg16[(tokb+0)*66 + c] = f2bf(p0);
        stg16[(tokb+1)*66 + c] = f2bf(p1);
        stg16[(tokb+2)*66 + c] = f2bf(p2);
        stg16[(tokb+3)*66 + c] = f2bf(p3);
        *(u32*)&stg8[c*132 + tokb] = pack4_e4(p0, p1, p2, p3);
      }
    }
  } else {
    #pragma unroll
    for (int i = 0; i < 4; i++){
      long gi = tM + wm*64 + i*16 + q*4;
      #pragma unroll
      for (int j = 0; j < 4; j++){
        int c = 64 + j*16 + r16;
        float bgc = bg[c];
        f32x4 v = acc[i][j];
        ushort4 o;
        o.x = f2bf(sigf(v[0] + bgc));
        o.y = f2bf(sigf(v[1] + bgc));
        o.z = f2bf(sigf(v[2] + bgc));
        o.w = f2bf(sigf(v[3] + bgc));
        *(ushort4*)(GT + (long)c*65536 + gi) = o;
      }
    }
  }
  __syncthreads();
  for (int e = tid; e < 8192; e += 256){        // D col dump (coalesced u16)
    int tok = e >> 6, c = e & 63;
    D[(tM + tok)*ldD + coloff + c] = stg16[tok*66 + c];
  }
  for (int e = tid; e < 2048; e += 256){        // Xr8 dump (u32)
    int c = e >> 5, seg = e & 31;
    *(u32*)(Xr8 + ((long)b*64 + c)*2048 + n0 + seg*4) = *(const u32*)&stg8[c*132 + seg*4];
  }
}

// ---------- fused dense + candidate epilogue ----------
// wn==0 waves (c<64): cv = bf16(tanh(acc+bc[c])); uv = GT[64+c][token] (pre-sigmoided);
// h = uv*hx + (1-uv)*cv -> hout (f32), optional Dnext col c (bf16), optional X0T rows (e4m3),
// optional wproj reduction -> out.
__global__ __launch_bounds__(256) void gemm_dense_cand(const u16* __restrict__ A, const u16* __restrict__ Bt,
                                                       int K, const float* __restrict__ bc,
                                                       const u16* __restrict__ GT,
                                                       const float* __restrict__ hx,
                                                       float* __restrict__ hout,
                                                       u8* __restrict__ X0T_next,
                                                       u16* __restrict__ Dnext, long ldDn, int colDn,
                                                       const float* __restrict__ wproj,
                                                       const float* __restrict__ bproj,
                                                       float* __restrict__ out){
  __shared__ __align__(16) u8 smem[32768];
  u16* lA = (u16*)smem;
  u16* lB = (u16*)(smem + 16384);
  f32x4 acc[4][4];
  long tM = (long)blockIdx.x * 128;
  gemm_core(A, Bt, K, tM, 0, lA, lB, acc);

  int tid = threadIdx.x, wv = tid >> 6, lane = tid & 63;
  int q = lane >> 4, r16 = lane & 15, wm = wv & 1, wn = wv >> 1;
  int b = (int)(tM >> 11), n0 = (int)(tM & 2047);
  u16* stg16 = (u16*)smem;          // [128][66] h bf16

  __syncthreads();
  if (wn == 0){
    #pragma unroll
    for (int i = 0; i < 4; i++){
      int tokb = wm*64 + i*16 + q*4;
      long gtok = tM + tokb;
      float psum0 = 0.f, psum1 = 0.f, psum2 = 0.f, psum3 = 0.f;
      #pragma unroll
      for (int j = 0; j < 4; j++){
        int c = j*16 + r16;
        float bcc = bc[c];
        float wpc = wproj ? wproj[c] : 0.f;
        f32x4 v = acc[i][j];
        #pragma unroll
        for (int rr = 0; rr < 4; rr++){
          float cv = bf2f(f2bf(tanhf(v[rr] + bcc)));
          float uv = bf2f(GT[(long)(64+c)*65536 + gtok + rr]);
          float hxv = hx[(gtok+rr)*64 + c];
          float h = uv*hxv + (1.f - uv)*cv;
          hout[(gtok+rr)*64 + c] = h;
          stg16[(tokb+rr)*66 + c] = f2bf(h);
          float hw = h * wpc;
          if (rr == 0) psum0 += hw; else if (rr == 1) psum1 += hw;
          else if (rr == 2) psum2 += hw; else psum3 += hw;
        }
      }
      if (wproj){
        float ps[4] = {psum0, psum1, psum2, psum3};
        #pragma unroll
        for (int rr = 0; rr < 4; rr++){
          float vv = ps[rr];
          vv += __shfl_xor(vv, 1, 64);
          vv += __shfl_xor(vv, 2, 64);
          vv += __shfl_xor(vv, 4, 64);
          vv += __shfl_xor(vv, 8, 64);
          if (r16 == 0) out[gtok + rr] = vv + bproj[0];
        }
      }
    }
  }
  __syncthreads();
  if (Dnext){
    for (int e = tid; e < 8192; e += 256){
      int tok = e >> 6, c = e & 63;
      Dnext[(tM + tok)*ldDn + colDn + c] = stg16[tok*66 + c];
    }
  }
  if (X0T_next){
    for (int e = tid; e < 8192; e += 256){
      int c = e >> 7, tok = e & 127;
      u16 hb = stg16[tok*66 + c];
      X0T_next[((long)b*128 + c)*2048 + n0 + tok] = f2e4(bf2f(hb));
    }
  }
}

// ---------- launch ----------
extern "C" void kernel_launch(void* const* d_in, const int* in_sizes, int n_in,
                              void* d_out, int out_size, void* d_ws, size_t ws_size,
                              hipStream_t stream){
  (void)in_sizes; (void)n_in; (void)out_size; (void)ws_size;
  const float* inputs = (const float*)d_in[0];
  const float* hidden = (const float*)d_in[1];
  const float* adj    = (const float*)d_in[2];
  const float* wg0 = (const float*)d_in[3];
  const float* bg0 = (const float*)d_in[4];
  const float* wc0 = (const float*)d_in[5];
  const float* bc0 = (const float*)d_in[6];
  const float* wg1 = (const float*)d_in[7];
  const float* bg1 = (const float*)d_in[8];
  const float* wc1 = (const float*)d_in[9];
  const float* bc1 = (const float*)d_in[10];
  const float* wp  = (const float*)d_in[11];
  const float* bp  = (const float*)d_in[12];
  float* out = (float*)d_out;

  char* p = (char*)d_ws;
  auto alloc = [&](size_t bytes)->char*{ char* r = p; p += (bytes + 255) & ~(size_t)255; return r; };
  float* inv_rs = (float*)alloc(2048*4);
  float* cs     = (float*)alloc(2048*4);
  const size_t SB  = (size_t)2048*2048*2;   // bf16 NxN
  const size_t SB8 = (size_t)2048*2048;     // fp8 NxN
  u16* S0  = (u16*)alloc(SB);
  u8*  S0q = (u8*)alloc(SB8);
  u8*  S0Tq= (u8*)alloc(SB8);
  u8*  S1q = (u8*)alloc(SB8);
  u8*  Rq  = (u8*)alloc(SB8);
  u8*  RTq = (u8*)alloc(SB8);
  u8*  Vq  = (u8*)alloc(SB8);
  u8*  Wq  = (u8*)alloc(SB8);
  u8*  X0a8 = (u8*)alloc((size_t)2304*2048); // layer0 cat, fp8, Fp=72
  u8*  X0b8 = (u8*)alloc((size_t)4096*2048); // layer1 cat, fp8, Fp=128
  u8*  Xr8  = (u8*)alloc(SB8);               // r*hx, fp8
  u16* D0  = (u16*)alloc((size_t)65536*384*2);   // layer0 dense input, ld 384
  u16* D1  = (u16*)alloc((size_t)65536*640*2);   // layer1 dense input, ld 640
  u16* GT = (u16*)alloc((size_t)128*65536*2);    // rows 64..127: pre-sigmoided update gate
  u16* WTg0 = (u16*)alloc((size_t)128*384*2);
  u16* WTc0 = (u16*)alloc((size_t)128*384*2);
  u16* WTg1 = (u16*)alloc((size_t)128*640*2);
  u16* WTc1 = (u16*)alloc((size_t)128*640*2);

  const float* hid0 = hidden;
  const float* hid1 = hidden + (size_t)4194304;
  float* h0out = out + 65536;
  float* h1out = out + 65536 + 4194304;

  // ---- setup ----
  k_rowsum<<<2048, 256, 0, stream>>>(adj, inv_rs, cs);
  k_colsum2<<<dim3(32,16), 256, 0, stream>>>(adj, cs);
  k_build_S<<<dim3(32,32), 256, 0, stream>>>(adj, inv_rs, cs, S0, S0q, S0Tq, S1q);
  k_packW4<<<dim3(320,4), 256, 0, stream>>>(wg0, wc0, wg1, wc1, WTg0, WTc0, WTg1, WTc1);
  k_hx_build<<<dim3(32,32), 256, 0, stream>>>(hid0, inputs, X0a8, D0, 72, 1, 384, 1, 1);

  // ---- precompute diffusion operators R, V, W (fp8 MX compute) ----
  gemm_pre8<<<dim3(16,16,2), 256, 0, stream>>>(S0Tq, S1q, S0q, Rq, RTq, Vq);
  gemm_w8  <<<dim3(16,16),   256, 0, stream>>>(RTq, S1q, S0, Wq);

  dim3 gD0(16, 18, 4), gD1(16, 32, 4), gDc(16, 16, 4), gDen(512, 1);

  // ---- layer 0 gate ----
  gemm_diff8<72><<<gD0, 256, 0, stream>>>(S0q, Vq, Rq, Wq, X0a8, D0, 384);
  gemm_dense_gate<<<gDen, 256, 0, stream>>>(D0, WTg0, 384, bg0, hid0, GT, Xr8, D0, 384, 1);

  // ---- layer 0 candidate (diffuse only r*hx; inp cols reused from gate pass) ----
  gemm_diff8_c<<<gDc, 256, 0, stream>>>(S0q, Vq, Rq, Wq, Xr8, D0, 384, 72, 1);
  gemm_dense_cand<<<gDen, 256, 0, stream>>>(D0, WTc0, 384, bc0, GT, hid0, h0out,
                                            X0b8, D1, 640, 0, nullptr, nullptr, nullptr);

  // ---- layer 1 build ----
  k_hx_build<<<dim3(32,32), 256, 0, stream>>>(hid1, nullptr, X0b8, D1, 128, 64, 640, 64, 0);

  // ---- layer 1 gate ----
  gemm_diff8<128><<<gD1, 256, 0, stream>>>(S0q, Vq, Rq, Wq, X0b8, D1, 640);
  gemm_dense_gate<<<gDen, 256, 0, stream>>>(D1, WTg1, 640, bg1, hid1, GT, Xr8, D1, 640, 64);

  // ---- layer 1 candidate ----
  gemm_diff8_c<<<gDc, 256, 0, stream>>>(S0q, Vq, Rq, Wq, Xr8, D1, 640, 128, 64);
  gemm_dense_cand<<<gDen, 256, 0, stream>>>(D1, WTc1, 640, bc1, GT, hid1, h1out,
                                            nullptr, nullptr, 0, 0, wp, bp, out);
}